// Round 6
// baseline (414.171 us; speedup 1.0000x reference)
//
#include <hip/hip_runtime.h>
#include <hip/hip_bf16.h>
#include <math.h>

// Problem dims (fixed)
#define BB 2
#define SS 512
#define DD 256
#define FFD 1024
#define HH 4
#define NN 512
#define PP 32
#define KK 16
#define KPP 4
#define RR 64
#define DHH 64
#define TT (BB*SS)   // 1024 tokens
#define QT 16        // attn queries per block

// ---------------------------------------------------------------------------
__global__ __launch_bounds__(64) void zero_kernel(int* __restrict__ p, int n)
{
    int i = threadIdx.x;
    if (i < n) p[i] = 0;
}

// ---------------------------------------------------------------------------
// LayerNorm: produces n1 = LN(x,g1,b1), n2 = LN(x,g2,b2). One block per token.
// ---------------------------------------------------------------------------
__global__ __launch_bounds__(256) void ln_kernel(
    const float* __restrict__ x,
    const float* __restrict__ g1, const float* __restrict__ b1,
    const float* __restrict__ g2, const float* __restrict__ b2,
    float* __restrict__ n1, float* __restrict__ n2)
{
    int t = blockIdx.x;
    int d = threadIdx.x;
    __shared__ float red[256];
    float v = x[t*DD + d];
    red[d] = v; __syncthreads();
    for (int s = 128; s > 0; s >>= 1) { if (d < s) red[d] += red[d+s]; __syncthreads(); }
    float mu = red[0] * (1.0f/DD);
    __syncthreads();
    float dv = v - mu;
    red[d] = dv*dv; __syncthreads();
    for (int s = 128; s > 0; s >>= 1) { if (d < s) red[d] += red[d+s]; __syncthreads(); }
    float var = red[0] * (1.0f/DD);
    float r = 1.0f / sqrtf(var + 1e-5f);
    n1[t*DD+d] = dv*r*g1[d] + b1[d];
    n2[t*DD+d] = dv*r*g2[d] + b2[d];
}

// ---------------------------------------------------------------------------
// GEMM body v2: 64x64 tile, BK=32, 256 threads, register double-buffering.
//   mode 0: none; 1: sigmoid; 2: gelu(0.1*val+0.9*sum4slices(extra)); 3: val+extra
// ---------------------------------------------------------------------------
__device__ __forceinline__ void gemm_body(
    const float* __restrict__ A, const float* __restrict__ Bm,
    const float* __restrict__ bias, const float* __restrict__ extra,
    float* __restrict__ C, int M, int Nn, int Kk, int transB, int mode,
    int k0off, int kLen)
{
    __shared__ float As[2][32][68];   // As[buf][k][m] (transposed)
    __shared__ float Bs[2][32][68];   // Bs[buf][k][n]
    int bm = blockIdx.y * 64;
    int bn = blockIdx.x * 64;
    int tid = threadIdx.x;
    int tx = tid & 15, ty = tid >> 4;

    float4 pa[2], pb[2];

    #define LOAD_A(kbase) { \
        _Pragma("unroll") \
        for (int e = 0; e < 2; ++e) { \
            int r = e*32 + (tid>>3); int c4 = tid & 7; \
            pa[e] = *(const float4*)&A[(size_t)(bm + r)*Kk + (kbase) + c4*4]; \
        } }
    #define STORE_A(buf) { \
        _Pragma("unroll") \
        for (int e = 0; e < 2; ++e) { \
            int r = e*32 + (tid>>3); int c4 = tid & 7; \
            As[buf][c4*4+0][r] = pa[e].x; \
            As[buf][c4*4+1][r] = pa[e].y; \
            As[buf][c4*4+2][r] = pa[e].z; \
            As[buf][c4*4+3][r] = pa[e].w; \
        } }
    #define LOAD_B(kbase) { \
        if (transB == 0) { \
            _Pragma("unroll") \
            for (int e = 0; e < 2; ++e) { \
                int c = e*16 + (tid>>4); int n4 = tid & 15; \
                pb[e] = *(const float4*)&Bm[(size_t)((kbase) + c)*Nn + bn + n4*4]; \
            } \
        } else { \
            _Pragma("unroll") \
            for (int e = 0; e < 2; ++e) { \
                int r = e*32 + (tid>>3); int k4 = tid & 7; \
                pb[e] = *(const float4*)&Bm[(size_t)(bn + r)*Kk + (kbase) + k4*4]; \
            } \
        } }
    #define STORE_B(buf) { \
        if (transB == 0) { \
            _Pragma("unroll") \
            for (int e = 0; e < 2; ++e) { \
                int c = e*16 + (tid>>4); int n4 = tid & 15; \
                *(float4*)&Bs[buf][c][n4*4] = pb[e]; \
            } \
        } else { \
            _Pragma("unroll") \
            for (int e = 0; e < 2; ++e) { \
                int r = e*32 + (tid>>3); int k4 = tid & 7; \
                Bs[buf][k4*4+0][r] = pb[e].x; \
                Bs[buf][k4*4+1][r] = pb[e].y; \
                Bs[buf][k4*4+2][r] = pb[e].z; \
                Bs[buf][k4*4+3][r] = pb[e].w; \
            } \
        } }

    float acc[4][4] = {};
    int nk = kLen >> 5;   // BK=32

    LOAD_A(k0off); LOAD_B(k0off);
    STORE_A(0); STORE_B(0);
    __syncthreads();

    for (int kt = 0; kt < nk; ++kt) {
        int cur = kt & 1;
        if (kt + 1 < nk) { LOAD_A(k0off + (kt+1)*32); LOAD_B(k0off + (kt+1)*32); }
        #pragma unroll
        for (int kk = 0; kk < 32; ++kk) {
            float4 av = *(const float4*)&As[cur][kk][ty*4];
            float4 bv = *(const float4*)&Bs[cur][kk][tx*4];
            acc[0][0] = fmaf(av.x, bv.x, acc[0][0]);
            acc[0][1] = fmaf(av.x, bv.y, acc[0][1]);
            acc[0][2] = fmaf(av.x, bv.z, acc[0][2]);
            acc[0][3] = fmaf(av.x, bv.w, acc[0][3]);
            acc[1][0] = fmaf(av.y, bv.x, acc[1][0]);
            acc[1][1] = fmaf(av.y, bv.y, acc[1][1]);
            acc[1][2] = fmaf(av.y, bv.z, acc[1][2]);
            acc[1][3] = fmaf(av.y, bv.w, acc[1][3]);
            acc[2][0] = fmaf(av.z, bv.x, acc[2][0]);
            acc[2][1] = fmaf(av.z, bv.y, acc[2][1]);
            acc[2][2] = fmaf(av.z, bv.z, acc[2][2]);
            acc[2][3] = fmaf(av.z, bv.w, acc[2][3]);
            acc[3][0] = fmaf(av.w, bv.x, acc[3][0]);
            acc[3][1] = fmaf(av.w, bv.y, acc[3][1]);
            acc[3][2] = fmaf(av.w, bv.z, acc[3][2]);
            acc[3][3] = fmaf(av.w, bv.w, acc[3][3]);
        }
        if (kt + 1 < nk) {
            STORE_A(cur^1); STORE_B(cur^1);
            __syncthreads();
        }
    }

    #pragma unroll
    for (int i = 0; i < 4; ++i) {
        int m = bm + ty*4 + i;
        #pragma unroll
        for (int j = 0; j < 4; ++j) {
            int n = bn + tx*4 + j;
            float val = acc[i][j] + (bias ? bias[n] : 0.0f);
            if (mode == 1) {
                val = 1.0f / (1.0f + expf(-val));
            } else if (mode == 2) {
                size_t idx = (size_t)m*Nn + n;
                float hp = extra[idx] + extra[idx + (size_t)TT*FFD]
                         + extra[idx + 2*(size_t)TT*FFD] + extra[idx + 3*(size_t)TT*FFD];
                float z = 0.1f*val + 0.9f*hp;
                val = 0.5f*z*(1.0f + erff(z*0.70710678118654752f));
            } else if (mode == 3) {
                val = val + extra[(size_t)m*Nn+n];
            }
            C[(size_t)m*Nn + n] = val;
        }
    }
    #undef LOAD_A
    #undef STORE_A
    #undef LOAD_B
    #undef STORE_B
}

__global__ __launch_bounds__(256) void gemm_kernel(
    const float* __restrict__ A, const float* __restrict__ Bm,
    const float* __restrict__ bias, const float* __restrict__ extra,
    float* __restrict__ C, int M, int Nn, int Kk, int transB, int mode)
{
    gemm_body(A, Bm, bias, extra, C, M, Nn, Kk, transB, mode, 0, Kk);
}

struct GemmSet { const float* A; const float* B; const float* bias; float* C; int mode; };

__global__ __launch_bounds__(256) void gemm3_kernel(
    GemmSet s0, GemmSet s1, GemmSet s2, int M, int Nn, int Kk, int transB)
{
    GemmSet s = (blockIdx.z == 0) ? s0 : ((blockIdx.z == 1) ? s1 : s2);
    gemm_body(s.A, s.B, s.bias, nullptr, s.C, M, Nn, Kk, transB, s.mode, 0, Kk);
}

__global__ __launch_bounds__(256) void gemm_splitk_kernel(
    const float* __restrict__ A, const float* __restrict__ Bm,
    float* __restrict__ Cpart, int M, int Nn, int Kk, int kPerSplit)
{
    int sk = blockIdx.z;
    float* Cp = Cpart + (size_t)sk * M * Nn;
    gemm_body(A, Bm, nullptr, nullptr, Cp, M, Nn, Kk, 0, 0, sk*kPerSplit, kPerSplit);
}

__global__ __launch_bounds__(256) void combine_wd_kernel(
    const float* __restrict__ part, const float* __restrict__ x,
    const float* __restrict__ bd, float* __restrict__ out)
{
    int i = blockIdx.x*256 + threadIdx.x;
    int d = i & (DD-1);
    float s = x[i] + bd[d];
    s += part[i] + part[i + TT*DD] + part[i + 2*TT*DD] + part[i + 3*TT*DD];
    out[i] = s;
}

// ---------------------------------------------------------------------------
// Flash-style attention: block = (b, h, 16-query tile). 256 blocks, 256 thr.
// ---------------------------------------------------------------------------
__global__ __launch_bounds__(256) void attn_kernel(
    const float* __restrict__ q, const float* __restrict__ k,
    const float* __restrict__ v, float* __restrict__ ctx)
{
    int bi = blockIdx.x;
    int qt = bi & 31;
    int bh = bi >> 5;
    int h = bh & (HH-1);
    int b = bh >> 2;
    int tid = threadIdx.x;
    int qo = tid >> 4;
    int c  = tid & 15;

    __shared__ float Qs[QT][68];
    __shared__ float Kt[64][64];
    __shared__ float Vs[64][68];
    __shared__ float Ps[QT][68];

    {
        const float* qp = q + ((size_t)(b*SS + qt*QT + qo)*DD) + h*DHH + c*4;
        *(float4*)&Qs[qo][c*4] = *(const float4*)qp;
    }
    float O0=0.f, O1=0.f, O2=0.f, O3=0.f;
    float mreg = -3.4e38f, lreg = 0.f;

    for (int t = 0; t < 8; ++t) {
        if (t) __syncthreads();
        #pragma unroll
        for (int e = 0; e < 4; ++e) {
            int lin = e*256 + tid;
            int kr = lin & 63;
            int c4 = lin >> 6;
            const float* kp = k + ((size_t)(b*SS + t*64 + kr)*DD) + h*DHH + c4*4;
            float4 kv = *(const float4*)kp;
            Kt[c4*4+0][kr] = kv.x;
            Kt[c4*4+1][kr] = kv.y;
            Kt[c4*4+2][kr] = kv.z;
            Kt[c4*4+3][kr] = kv.w;
            int vr = lin >> 4;
            int vc = lin & 15;
            const float* vp = v + ((size_t)(b*SS + t*64 + vr)*DD) + h*DHH + vc*4;
            *(float4*)&Vs[vr][vc*4] = *(const float4*)vp;
        }
        __syncthreads();
        float s0=0.f, s1=0.f, s2=0.f, s3=0.f;
        #pragma unroll 8
        for (int d = 0; d < 64; ++d) {
            float qv = Qs[qo][d];
            float4 kv = *(const float4*)&Kt[d][c*4];
            s0 = fmaf(qv, kv.x, s0);
            s1 = fmaf(qv, kv.y, s1);
            s2 = fmaf(qv, kv.z, s2);
            s3 = fmaf(qv, kv.w, s3);
        }
        s0 *= 0.125f; s1 *= 0.125f; s2 *= 0.125f; s3 *= 0.125f;
        float mx = fmaxf(fmaxf(s0, s1), fmaxf(s2, s3));
        #pragma unroll
        for (int mk = 1; mk <= 8; mk <<= 1)
            mx = fmaxf(mx, __shfl_xor(mx, mk));
        float mnew = fmaxf(mreg, mx);
        float scl = __expf(mreg - mnew);
        float e0 = __expf(s0 - mnew), e1 = __expf(s1 - mnew),
              e2 = __expf(s2 - mnew), e3 = __expf(s3 - mnew);
        float esum = e0 + e1 + e2 + e3;
        #pragma unroll
        for (int mk = 1; mk <= 8; mk <<= 1)
            esum += __shfl_xor(esum, mk);
        lreg = lreg * scl + esum;
        mreg = mnew;
        float4 pw; pw.x = e0; pw.y = e1; pw.z = e2; pw.w = e3;
        *(float4*)&Ps[qo][c*4] = pw;
        __syncthreads();
        O0 *= scl; O1 *= scl; O2 *= scl; O3 *= scl;
        #pragma unroll 8
        for (int kk = 0; kk < 64; ++kk) {
            float pv = Ps[qo][kk];
            float4 vv = *(const float4*)&Vs[kk][c*4];
            O0 = fmaf(pv, vv.x, O0);
            O1 = fmaf(pv, vv.y, O1);
            O2 = fmaf(pv, vv.z, O2);
            O3 = fmaf(pv, vv.w, O3);
        }
    }
    float linv = 1.0f / lreg;
    float4 o4; o4.x = O0*linv; o4.y = O1*linv; o4.z = O2*linv; o4.w = O3*linv;
    *(float4*)(ctx + ((size_t)(b*SS + qt*QT + qo)*DD) + h*DHH + c*4) = o4;
}

// ---------------------------------------------------------------------------
// Path softmax + score mix + stable top-16 (shfl-based). Block per token.
// ---------------------------------------------------------------------------
__global__ __launch_bounds__(256) void route_kernel(
    const float* __restrict__ n1, const float* __restrict__ ctx,
    const float* __restrict__ Wpath, const float* __restrict__ bpath,
    const float* __restrict__ ts, const float* __restrict__ cs,
    int* __restrict__ topk_idx, float* __restrict__ topk_w,
    float* __restrict__ out_idx)
{
    int t = blockIdx.x, tid = threadIdx.x;
    int wv = tid >> 6;
    __shared__ float pw0[4], pw1[4];
    float a = n1[t*DD+tid], c = ctx[t*DD+tid];
    float r0 = a * Wpath[tid*2+0] + c * Wpath[(DD+tid)*2+0];
    float r1 = a * Wpath[tid*2+1] + c * Wpath[(DD+tid)*2+1];
    #pragma unroll
    for (int off = 1; off < 64; off <<= 1) {
        r0 += __shfl_xor(r0, off);
        r1 += __shfl_xor(r1, off);
    }
    if ((tid & 63) == 0) { pw0[wv] = r0; pw1[wv] = r1; }
    __syncthreads();
    __shared__ float w0s, w1s;
    if (tid == 0) {
        float l0 = pw0[0]+pw0[1]+pw0[2]+pw0[3] + bpath[0];
        float l1 = pw1[0]+pw1[1]+pw1[2]+pw1[3] + bpath[1];
        float mm = fmaxf(l0, l1);
        float e0 = expf(l0-mm), e1 = expf(l1-mm);
        float is = 1.0f/(e0+e1);
        w0s = e0*is; w1s = e1*is;
    }
    __syncthreads();
    float w0 = w0s, w1 = w1s;
    __shared__ float sc[NN];
    sc[tid]     = w0*ts[t*NN+tid]     + w1*cs[t*NN+tid];
    sc[tid+256] = w0*ts[t*NN+tid+256] + w1*cs[t*NN+tid+256];
    __syncthreads();
    __shared__ float wvv[4]; __shared__ int wvi[4];
    __shared__ float selv[KK]; __shared__ int seli[KK];
    for (int it = 0; it < KK; ++it) {
        float v0 = sc[tid], v1 = sc[tid+256];
        float bv; int bi;
        if (v0 >= v1) { bv = v0; bi = tid; } else { bv = v1; bi = tid+256; }
        #pragma unroll
        for (int off = 1; off < 64; off <<= 1) {
            float ov = __shfl_xor(bv, off);
            int   oi = __shfl_xor(bi, off);
            if (ov > bv || (ov == bv && oi < bi)) { bv = ov; bi = oi; }
        }
        if ((tid & 63) == 0) { wvv[wv] = bv; wvi[wv] = bi; }
        __syncthreads();
        if (tid == 0) {
            float fv = wvv[0]; int fi = wvi[0];
            #pragma unroll
            for (int w = 1; w < 4; ++w) {
                float ov = wvv[w]; int oi = wvi[w];
                if (ov > fv || (ov == fv && oi < fi)) { fv = ov; fi = oi; }
            }
            selv[it] = fv; seli[it] = fi; sc[fi] = -3.4e38f;
        }
        __syncthreads();
    }
    if (tid == 0) {
        float mx = selv[0];
        float e[KK]; float sum = 0.f;
        for (int i = 0; i < KK; ++i) { e[i] = expf(selv[i]-mx); sum += e[i]; }
        float is = 1.0f/sum;
        for (int i = 0; i < KK; ++i) {
            topk_idx[t*KK+i] = seli[i];
            topk_w[t*KK+i]   = e[i]*is;
            out_idx[t*KK+i]  = (float)seli[i];
        }
    }
}

// ---------------------------------------------------------------------------
// InteractionFFN: block per token (rows padded 257: bank-conflict-free).
// ---------------------------------------------------------------------------
__global__ __launch_bounds__(256) void interact_kernel(
    const float* __restrict__ neurons,
    const float* __restrict__ nqa, const float* __restrict__ nka,
    const float* __restrict__ nva,
    const int* __restrict__ topk_idx, const float* __restrict__ topk_w,
    float* __restrict__ agg)
{
    int t = blockIdx.x, tid = threadIdx.x;
    __shared__ float nq[KK][DD+1];
    __shared__ float nk[KK][DD+1];
    __shared__ float nv[KK][DD+1];
    __shared__ float ps[HH][KK][KK];
    __shared__ float tw[KK];
    __shared__ int sidx[KK];
    if (tid < KK) { tw[tid] = topk_w[t*KK+tid]; sidx[tid] = topk_idx[t*KK+tid]; }
    __syncthreads();
    for (int i = 0; i < KK; ++i) {
        int idx = sidx[i];
        nq[i][tid] = nqa[idx*DD+tid];
        nk[i][tid] = nka[idx*DD+tid];
        nv[i][tid] = nva[idx*DD+tid];
    }
    __syncthreads();
    #pragma unroll
    for (int r = 0; r < 4; ++r) {
        int lin = r*256 + tid;         // (h,i,j)
        int j = lin & 15, i = (lin >> 4) & 15, h = lin >> 8;
        const float* qp = &nq[i][h*DHH];
        const float* kp = &nk[j][h*DHH];
        float acc = 0.f;
        #pragma unroll 8
        for (int d = 0; d < DHH; ++d) acc = fmaf(qp[d], kp[d], acc);
        ps[h][i][j] = acc * 0.125f;
    }
    __syncthreads();
    if (tid < 64) {
        int h = tid >> 4, i = tid & 15;
        float mx = -3.4e38f;
        for (int j = 0; j < KK; ++j) mx = fmaxf(mx, ps[h][i][j]);
        float sum = 0.f;
        for (int j = 0; j < KK; ++j) { float e = expf(ps[h][i][j]-mx); ps[h][i][j] = e; sum += e; }
        float is = 1.0f/sum;
        for (int j = 0; j < KK; ++j) ps[h][i][j] *= is;
    }
    __syncthreads();
    int d = tid, h = d >> 6;
    float acc = 0.f;
    for (int i = 0; i < KK; ++i) {
        float g = 0.f;
        #pragma unroll
        for (int j = 0; j < KK; ++j) g = fmaf(ps[h][i][j], nv[j][d], g);
        acc += tw[i] * neurons[sidx[i]*DD + d] * g;
    }
    agg[t*DD+d] = acc;
}

// ---------------------------------------------------------------------------
// Pattern select: per-token scores, stable top-4, comb; bins (token,kp) by
// pattern for the grouped mid/apply kernels.
// ---------------------------------------------------------------------------
__global__ __launch_bounds__(256) void pattern_select(
    const float* __restrict__ aggp, const float* __restrict__ ctxp,
    const float* __restrict__ n2p, const float* __restrict__ PQ,
    float* __restrict__ combined, float* __restrict__ tpwg,
    int* __restrict__ bin_count, int* __restrict__ bin_entry)
{
    int t = blockIdx.x, tid = threadIdx.x;
    __shared__ float mix[DD];
    __shared__ float ps[PP];
    __shared__ float psp[8][33];
    __shared__ int tpi[KPP];

    float a = aggp[t*DD+tid];
    float cx = ctxp[t*DD+tid];
    mix[tid] = 0.03125f * a + 0.5f * cx;   // 0.5/sqrt(256) = 0.03125
    combined[t*DD+tid] = n2p[t*DD+tid] + a;
    __syncthreads();

    {
        int p = tid & 31, g = tid >> 5;
        const float* pq = PQ + p*DD + g*32;
        const float* mp = mix + g*32;
        float acc = 0.f;
        #pragma unroll
        for (int d = 0; d < 32; ++d) acc = fmaf(mp[d], pq[d], acc);
        psp[g][p] = acc;
    }
    __syncthreads();
    if (tid < PP) {
        float s = 0.f;
        #pragma unroll
        for (int g = 0; g < 8; ++g) s += psp[g][tid];
        ps[tid] = s;
    }
    __syncthreads();

    if (tid == 0) {
        float vals[KPP];
        #pragma unroll
        for (int it = 0; it < KPP; ++it) {
            float bv = -3.4e38f; int bi = 0;
            for (int p = 0; p < PP; ++p) { float v = ps[p]; if (v > bv) { bv = v; bi = p; } }
            vals[it] = bv; tpi[it] = bi; ps[bi] = -3.4e38f;
        }
        float mx = vals[0];
        float e0 = expf(vals[0]-mx), e1 = expf(vals[1]-mx),
              e2 = expf(vals[2]-mx), e3 = expf(vals[3]-mx);
        float is = 1.0f/(e0+e1+e2+e3);
        tpwg[t*4+0]=e0*is; tpwg[t*4+1]=e1*is; tpwg[t*4+2]=e2*is; tpwg[t*4+3]=e3*is;
    }
    __syncthreads();
    if (tid < KPP) {
        int p = tpi[tid];
        int slot = atomicAdd(&bin_count[p], 1);
        bin_entry[p*TT + slot] = (t << 2) | tid;
    }
}

// ---------------------------------------------------------------------------
// LoRA mid: grid (PP, 8). Block (p,sub) stages A[p] (64KB) in LDS, then
// processes entry chunks sub, sub+8, ... of 16 entries. Thread = (entry, 4 r).
// Writes hmid_g[e][64] (tpw folded), e = (t<<2)|kp.
// ---------------------------------------------------------------------------
__global__ __launch_bounds__(256) void lora_mid(
    const float* __restrict__ comb, const float* __restrict__ tpwg,
    const int* __restrict__ bin_count, const int* __restrict__ bin_entry,
    const float* __restrict__ Aup, float* __restrict__ hmid_g)
{
    int p = blockIdx.x, sub = blockIdx.y;
    int cnt = bin_count[p];
    if (sub * 16 >= cnt) return;
    int tid = threadIdx.x;

    __shared__ float As[DD][RR];       // 64 KB; b128 reads 2-way at worst
    __shared__ float combs[16][DD+4];  // pad 4: i-groups hit distinct banks
    __shared__ int es[16];

    const float* Ap = Aup + (size_t)p*(DD*RR);
    #pragma unroll
    for (int e = 0; e < 64; ++e) {
        int lin = e*256 + tid;         // over 16384 float4s
        int d = lin >> 4, rg = lin & 15;
        *(float4*)&As[d][rg*4] = *(const float4*)&Ap[(size_t)d*RR + rg*4];
    }

    for (int base = sub*16; base < cnt; base += 8*16) {
        int nt = cnt - base; if (nt > 16) nt = 16;
        __syncthreads();               // also covers As on first iteration
        if (tid < 16) es[tid] = (tid < nt) ? bin_entry[p*TT + base + tid] : -1;
        __syncthreads();
        #pragma unroll
        for (int i = 0; i < 16; ++i) {
            int e = es[i];
            combs[i][tid] = (e >= 0) ? comb[(size_t)(e >> 2)*DD + tid] : 0.f;
        }
        __syncthreads();

        int i = tid >> 4, rg = tid & 15;
        float a0=0.f, a1=0.f, a2=0.f, a3=0.f;
        #pragma unroll 8
        for (int d = 0; d < DD; ++d) {
            float cv = combs[i][d];
            float4 av = *(const float4*)&As[d][rg*4];
            a0 = fmaf(cv, av.x, a0);
            a1 = fmaf(cv, av.y, a1);
            a2 = fmaf(cv, av.z, a2);
            a3 = fmaf(cv, av.w, a3);
        }
        int e = es[i];
        if (e >= 0) {
            float w = tpwg[e];         // tpwg[t*4+kp] == tpwg[e]
            float4 o; o.x = a0*w; o.y = a1*w; o.z = a2*w; o.w = a3*w;
            *(float4*)&hmid_g[(size_t)e*RR + rg*4] = o;
        }
    }
}

// ---------------------------------------------------------------------------
// LoRA apply: grid (PP, FFD/128). Block (p, fftile) stages B[p][:,128 cols]
// (33KB) once; loops 64-entry chunks (hmid tile 17KB in LDS). Thread =
// (8 entries x 4 cols) -> acc[8] float4 (32 VGPR), VALU-bound inner loop.
// ---------------------------------------------------------------------------
__global__ __launch_bounds__(256) void lora_apply(
    const int* __restrict__ bin_count, const int* __restrict__ bin_entry,
    const float* __restrict__ hmid_g, const float* __restrict__ Bup,
    float* __restrict__ hpat4)
{
    int p = blockIdx.x, ff0 = blockIdx.y * 128;
    int cnt = bin_count[p];
    int tid = threadIdx.x;

    __shared__ float Bs[RR][132];      // 33.8 KB
    __shared__ float hm[64][68];       // 17.4 KB
    __shared__ int es[64];

    const float* Bp = Bup + (size_t)p*(RR*FFD) + ff0;
    #pragma unroll
    for (int e = 0; e < 8; ++e) {
        int lin = e*256 + tid;         // over 2048 float4s
        int r = lin >> 5, cg = lin & 31;
        *(float4*)&Bs[r][cg*4] = *(const float4*)&Bp[(size_t)r*FFD + cg*4];
    }

    int eg = tid >> 5, cg = tid & 31;  // 8 entries x 4 cols per thread

    for (int base = 0; base < cnt; base += 64) {
        int nt = cnt - base; if (nt > 64) nt = 64;
        __syncthreads();               // also covers Bs on first iteration
        if (tid < 64) es[tid] = (tid < nt) ? bin_entry[p*TT + base + tid] : -1;
        __syncthreads();
        #pragma unroll
        for (int e = 0; e < 4; ++e) {
            int lin = e*256 + tid;     // over 1024 float4s (64 x 16)
            int i = lin >> 4, rg = lin & 15;
            int ei = es[i];
            float4 hv = make_float4(0.f,0.f,0.f,0.f);
            if (ei >= 0) hv = *(const float4*)&hmid_g[(size_t)ei*RR + rg*4];
            *(float4*)&hm[i][rg*4] = hv;
        }
        __syncthreads();

        float4 acc[8];
        #pragma unroll
        for (int j = 0; j < 8; ++j) acc[j] = make_float4(0.f,0.f,0.f,0.f);
        #pragma unroll 4
        for (int r = 0; r < RR; ++r) {
            float4 b = *(const float4*)&Bs[r][cg*4];
            #pragma unroll
            for (int j = 0; j < 8; ++j) {
                float h = hm[eg*8+j][r];
                acc[j].x = fmaf(h, b.x, acc[j].x);
                acc[j].y = fmaf(h, b.y, acc[j].y);
                acc[j].z = fmaf(h, b.z, acc[j].z);
                acc[j].w = fmaf(h, b.w, acc[j].w);
            }
        }
        #pragma unroll
        for (int j = 0; j < 8; ++j) {
            int e = es[eg*8+j];
            if (e >= 0) {
                int t = e >> 2, kp = e & 3;
                *(float4*)&hpat4[(size_t)kp*(TT*FFD) + (size_t)t*FFD + ff0 + cg*4] = acc[j];
            }
        }
    }
}

// ---------------------------------------------------------------------------
extern "C" void kernel_launch(void* const* d_in, const int* in_sizes, int n_in,
                              void* d_out, int out_size, void* d_ws, size_t ws_size,
                              hipStream_t stream)
{
    const float* x        = (const float*)d_in[0];
    const float* g1       = (const float*)d_in[1];
    const float* b1       = (const float*)d_in[2];
    const float* g2       = (const float*)d_in[3];
    const float* b2       = (const float*)d_in[4];
    const float* Wq       = (const float*)d_in[5];
    const float* bq       = (const float*)d_in[6];
    const float* Wk       = (const float*)d_in[7];
    const float* bk       = (const float*)d_in[8];
    const float* Wv       = (const float*)d_in[9];
    const float* bv       = (const float*)d_in[10];
    const float* Wpath    = (const float*)d_in[11];
    const float* bpath    = (const float*)d_in[12];
    const float* neurons  = (const float*)d_in[13];
    const float* Wnq      = (const float*)d_in[14];
    const float* bnq      = (const float*)d_in[15];
    const float* Wnk      = (const float*)d_in[16];
    const float* bnk      = (const float*)d_in[17];
    const float* Wnv      = (const float*)d_in[18];
    const float* bnv      = (const float*)d_in[19];
    const float* PQ       = (const float*)d_in[20];
    const float* Aup      = (const float*)d_in[21];
    const float* Bup      = (const float*)d_in[22];
    const float* Wub      = (const float*)d_in[23];
    const float* bub      = (const float*)d_in[24];
    const float* Wd       = (const float*)d_in[25];
    const float* bd       = (const float*)d_in[26];

    float* out0    = (float*)d_out;              // [B,S,D] residual output
    float* out_idx = out0 + (size_t)TT*DD;       // [B,S,K] indices (as float)

    // workspace carve-up (floats)
    float* ws = (float*)d_ws;
    float* n1    = ws; ws += TT*DD;
    float* n2    = ws; ws += TT*DD;
    float* qb    = ws; ws += TT*DD;
    float* kb    = ws; ws += TT*DD;
    float* vb    = ws; ws += TT*DD;
    float* ctx   = ws; ws += TT*DD;
    float* ts    = ws; ws += TT*NN;
    float* cs    = ws; ws += TT*NN;
    float* nqa   = ws; ws += NN*DD;
    float* nka   = ws; ws += NN*DD;
    float* nva   = ws; ws += NN*DD;
    float* agg   = ws; ws += TT*DD;
    float* comb  = ws; ws += TT*DD;
    float* hpat4 = ws; ws += 4*TT*FFD;           // 4 slices (one per kp)
    float* hb    = ws; ws += TT*FFD;
    float* part  = ws; ws += 4*TT*DD;            // split-K partials for Wd
    float* hmidg = ws; ws += 4*TT*RR;            // hmid per entry e=(t<<2)|kp
    float* tkw   = ws; ws += TT*KK;
    float* tpwg  = ws; ws += TT*KPP;
    int*   tki   = (int*)ws; ws += TT*KK;
    int*   binc  = (int*)ws; ws += 32;
    int*   bine  = (int*)ws; ws += 32*TT;

    dim3 blk(256);

    // 0. zero bin counters (ws is re-poisoned before every call)
    zero_kernel<<<1, 64, 0, stream>>>(binc, 32);

    // 1. LayerNorms
    ln_kernel<<<TT, blk, 0, stream>>>(x, g1, b1, g2, b2, n1, n2);

    // 2. QKV projections batched (M=1024,N=256,K=256, z=3)
    {
        GemmSet sq{n1, Wq, bq, qb, 0}, sk{n1, Wk, bk, kb, 0}, sv{n1, Wv, bv, vb, 0};
        gemm3_kernel<<<dim3(DD/64, TT/64, 3), blk, 0, stream>>>(sq, sk, sv, TT, DD, DD, 0);
    }

    // 3. Neuron projections batched (M=512,N=256,K=256, z=3); nv -> sigmoid
    {
        GemmSet s0{neurons, Wnq, bnq, nqa, 0}, s1{neurons, Wnk, bnk, nka, 0},
                s2{neurons, Wnv, bnv, nva, 1};
        gemm3_kernel<<<dim3(DD/64, NN/64, 3), blk, 0, stream>>>(s0, s1, s2, NN, DD, DD, 0);
    }

    // 4. Attention -> context  (flash-style, 256 blocks)
    attn_kernel<<<BB*HH*(SS/QT), blk, 0, stream>>>(qb, kb, vb, ctx);

    // 5. token/context scores vs neurons^T (M=1024,N=512,K=256, transB, z=2)
    {
        GemmSet s0{n1, neurons, nullptr, ts, 0}, s1{ctx, neurons, nullptr, cs, 0};
        gemm3_kernel<<<dim3(NN/64, TT/64, 2), blk, 0, stream>>>(s0, s1, s1, TT, NN, DD, 1);
    }

    // 6. path weights + mix + top-16
    route_kernel<<<TT, blk, 0, stream>>>(n1, ctx, Wpath, bpath, ts, cs, tki, tkw, out_idx);

    // 7. interaction FFN -> aggregated
    interact_kernel<<<TT, blk, 0, stream>>>(neurons, nqa, nka, nva, tki, tkw, agg);

    // 8a. pattern select -> comb, tpw, bins
    pattern_select<<<TT, blk, 0, stream>>>(agg, ctx, n2, PQ, comb, tpwg, binc, bine);

    // 8b. LoRA mid (A in LDS, grouped by pattern) -> hmid_g
    lora_mid<<<dim3(PP, 8), blk, 0, stream>>>(comb, tpwg, binc, bine, Aup, hmidg);

    // 8c. LoRA apply (B tile in LDS, grouped by pattern) -> hpat4 slices
    lora_apply<<<dim3(PP, FFD/128), blk, 0, stream>>>(binc, bine, hmidg, Bup, hpat4);

    // 9. h = gelu(0.1*(comb@Wub+bub) + 0.9*sum(hpat4))   (M=1024,N=1024,K=256)
    gemm_kernel<<<dim3(FFD/64, TT/64), blk, 0, stream>>>(comb, Wub, bub, hpat4, hb, TT, FFD, DD, 0, 2);

    // 10. out = x + h@Wd + bd  via split-K(4) + combine  (M=1024,N=256,K=1024)
    gemm_splitk_kernel<<<dim3(DD/64, TT/64, 4), blk, 0, stream>>>(hb, Wd, part, TT, DD, FFD, FFD/4);
    combine_wd_kernel<<<TT*DD/256, blk, 0, stream>>>(part, x, bd, out0);
}

// Round 7
// 403.366 us; speedup vs baseline: 1.0268x; 1.0268x over previous
//
#include <hip/hip_runtime.h>
#include <hip/hip_bf16.h>
#include <math.h>

// Problem dims (fixed)
#define BB 2
#define SS 512
#define DD 256
#define FFD 1024
#define HH 4
#define NN 512
#define PP 32
#define KK 16
#define KPP 4
#define RR 64
#define DHH 64
#define TT (BB*SS)   // 1024 tokens
#define QT 16        // attn queries per block

// ---------------------------------------------------------------------------
// LayerNorm (+ zero the 32 bin counters from block 0). One block per token.
// ---------------------------------------------------------------------------
__global__ __launch_bounds__(256) void ln_kernel(
    const float* __restrict__ x,
    const float* __restrict__ g1, const float* __restrict__ b1,
    const float* __restrict__ g2, const float* __restrict__ b2,
    float* __restrict__ n1, float* __restrict__ n2,
    int* __restrict__ binc)
{
    int t = blockIdx.x;
    int d = threadIdx.x;
    if (t == 0 && d < 32) binc[d] = 0;
    __shared__ float red[256];
    float v = x[t*DD + d];
    red[d] = v; __syncthreads();
    for (int s = 128; s > 0; s >>= 1) { if (d < s) red[d] += red[d+s]; __syncthreads(); }
    float mu = red[0] * (1.0f/DD);
    __syncthreads();
    float dv = v - mu;
    red[d] = dv*dv; __syncthreads();
    for (int s = 128; s > 0; s >>= 1) { if (d < s) red[d] += red[d+s]; __syncthreads(); }
    float var = red[0] * (1.0f/DD);
    float r = 1.0f / sqrtf(var + 1e-5f);
    n1[t*DD+d] = dv*r*g1[d] + b1[d];
    n2[t*DD+d] = dv*r*g2[d] + b2[d];
}

// ---------------------------------------------------------------------------
// GEMM body: 64x64 tile, BK=32, 256 threads, register double-buffering.
//   mode 0: none; 1: sigmoid; 2: gelu(0.1*val+0.9*sum4slices(extra)); 3: val+extra
// ---------------------------------------------------------------------------
__device__ __forceinline__ void gemm_body(
    const float* __restrict__ A, const float* __restrict__ Bm,
    const float* __restrict__ bias, const float* __restrict__ extra,
    float* __restrict__ C, int M, int Nn, int Kk, int transB, int mode,
    int k0off, int kLen)
{
    __shared__ float As[2][32][68];   // As[buf][k][m] (transposed)
    __shared__ float Bs[2][32][68];   // Bs[buf][k][n]
    int bm = blockIdx.y * 64;
    int bn = blockIdx.x * 64;
    int tid = threadIdx.x;
    int tx = tid & 15, ty = tid >> 4;

    float4 pa[2], pb[2];

    #define LOAD_A(kbase) { \
        _Pragma("unroll") \
        for (int e = 0; e < 2; ++e) { \
            int r = e*32 + (tid>>3); int c4 = tid & 7; \
            pa[e] = *(const float4*)&A[(size_t)(bm + r)*Kk + (kbase) + c4*4]; \
        } }
    #define STORE_A(buf) { \
        _Pragma("unroll") \
        for (int e = 0; e < 2; ++e) { \
            int r = e*32 + (tid>>3); int c4 = tid & 7; \
            As[buf][c4*4+0][r] = pa[e].x; \
            As[buf][c4*4+1][r] = pa[e].y; \
            As[buf][c4*4+2][r] = pa[e].z; \
            As[buf][c4*4+3][r] = pa[e].w; \
        } }
    #define LOAD_B(kbase) { \
        if (transB == 0) { \
            _Pragma("unroll") \
            for (int e = 0; e < 2; ++e) { \
                int c = e*16 + (tid>>4); int n4 = tid & 15; \
                pb[e] = *(const float4*)&Bm[(size_t)((kbase) + c)*Nn + bn + n4*4]; \
            } \
        } else { \
            _Pragma("unroll") \
            for (int e = 0; e < 2; ++e) { \
                int r = e*32 + (tid>>3); int k4 = tid & 7; \
                pb[e] = *(const float4*)&Bm[(size_t)(bn + r)*Kk + (kbase) + k4*4]; \
            } \
        } }
    #define STORE_B(buf) { \
        if (transB == 0) { \
            _Pragma("unroll") \
            for (int e = 0; e < 2; ++e) { \
                int c = e*16 + (tid>>4); int n4 = tid & 15; \
                *(float4*)&Bs[buf][c][n4*4] = pb[e]; \
            } \
        } else { \
            _Pragma("unroll") \
            for (int e = 0; e < 2; ++e) { \
                int r = e*32 + (tid>>3); int k4 = tid & 7; \
                Bs[buf][k4*4+0][r] = pb[e].x; \
                Bs[buf][k4*4+1][r] = pb[e].y; \
                Bs[buf][k4*4+2][r] = pb[e].z; \
                Bs[buf][k4*4+3][r] = pb[e].w; \
            } \
        } }

    float acc[4][4] = {};
    int nk = kLen >> 5;   // BK=32

    LOAD_A(k0off); LOAD_B(k0off);
    STORE_A(0); STORE_B(0);
    __syncthreads();

    for (int kt = 0; kt < nk; ++kt) {
        int cur = kt & 1;
        if (kt + 1 < nk) { LOAD_A(k0off + (kt+1)*32); LOAD_B(k0off + (kt+1)*32); }
        #pragma unroll
        for (int kk = 0; kk < 32; ++kk) {
            float4 av = *(const float4*)&As[cur][kk][ty*4];
            float4 bv = *(const float4*)&Bs[cur][kk][tx*4];
            acc[0][0] = fmaf(av.x, bv.x, acc[0][0]);
            acc[0][1] = fmaf(av.x, bv.y, acc[0][1]);
            acc[0][2] = fmaf(av.x, bv.z, acc[0][2]);
            acc[0][3] = fmaf(av.x, bv.w, acc[0][3]);
            acc[1][0] = fmaf(av.y, bv.x, acc[1][0]);
            acc[1][1] = fmaf(av.y, bv.y, acc[1][1]);
            acc[1][2] = fmaf(av.y, bv.z, acc[1][2]);
            acc[1][3] = fmaf(av.y, bv.w, acc[1][3]);
            acc[2][0] = fmaf(av.z, bv.x, acc[2][0]);
            acc[2][1] = fmaf(av.z, bv.y, acc[2][1]);
            acc[2][2] = fmaf(av.z, bv.z, acc[2][2]);
            acc[2][3] = fmaf(av.z, bv.w, acc[2][3]);
            acc[3][0] = fmaf(av.w, bv.x, acc[3][0]);
            acc[3][1] = fmaf(av.w, bv.y, acc[3][1]);
            acc[3][2] = fmaf(av.w, bv.z, acc[3][2]);
            acc[3][3] = fmaf(av.w, bv.w, acc[3][3]);
        }
        if (kt + 1 < nk) {
            STORE_A(cur^1); STORE_B(cur^1);
            __syncthreads();
        }
    }

    #pragma unroll
    for (int i = 0; i < 4; ++i) {
        int m = bm + ty*4 + i;
        #pragma unroll
        for (int j = 0; j < 4; ++j) {
            int n = bn + tx*4 + j;
            float val = acc[i][j] + (bias ? bias[n] : 0.0f);
            if (mode == 1) {
                val = 1.0f / (1.0f + expf(-val));
            } else if (mode == 2) {
                size_t idx = (size_t)m*Nn + n;
                float hp = extra[idx] + extra[idx + (size_t)TT*FFD]
                         + extra[idx + 2*(size_t)TT*FFD] + extra[idx + 3*(size_t)TT*FFD];
                float z = 0.1f*val + 0.9f*hp;
                val = 0.5f*z*(1.0f + erff(z*0.70710678118654752f));
            } else if (mode == 3) {
                val = val + extra[(size_t)m*Nn+n];
            }
            C[(size_t)m*Nn + n] = val;
        }
    }
    #undef LOAD_A
    #undef STORE_A
    #undef LOAD_B
    #undef STORE_B
}

__global__ __launch_bounds__(256) void gemm_kernel(
    const float* __restrict__ A, const float* __restrict__ Bm,
    const float* __restrict__ bias, const float* __restrict__ extra,
    float* __restrict__ C, int M, int Nn, int Kk, int transB, int mode)
{
    gemm_body(A, Bm, bias, extra, C, M, Nn, Kk, transB, mode, 0, Kk);
}

struct GemmSet { const float* A; const float* B; const float* bias; float* C; int mode; };

__global__ __launch_bounds__(256) void gemm3_kernel(
    GemmSet s0, GemmSet s1, GemmSet s2, int M, int Nn, int Kk, int transB)
{
    GemmSet s = (blockIdx.z == 0) ? s0 : ((blockIdx.z == 1) ? s1 : s2);
    gemm_body(s.A, s.B, s.bias, nullptr, s.C, M, Nn, Kk, transB, s.mode, 0, Kk);
}

__global__ __launch_bounds__(256) void gemm_splitk_kernel(
    const float* __restrict__ A, const float* __restrict__ Bm,
    float* __restrict__ Cpart, int M, int Nn, int Kk, int kPerSplit)
{
    int sk = blockIdx.z;
    float* Cp = Cpart + (size_t)sk * M * Nn;
    gemm_body(A, Bm, nullptr, nullptr, Cp, M, Nn, Kk, 0, 0, sk*kPerSplit, kPerSplit);
}

__global__ __launch_bounds__(256) void combine_wd_kernel(
    const float* __restrict__ part, const float* __restrict__ x,
    const float* __restrict__ bd, float* __restrict__ out)
{
    int i = blockIdx.x*256 + threadIdx.x;
    int d = i & (DD-1);
    float s = x[i] + bd[d];
    s += part[i] + part[i + TT*DD] + part[i + 2*TT*DD] + part[i + 3*TT*DD];
    out[i] = s;
}

// ---------------------------------------------------------------------------
// Flash-style attention: block = (b, h, 16-query tile). 256 blocks, 256 thr.
// ---------------------------------------------------------------------------
__global__ __launch_bounds__(256) void attn_kernel(
    const float* __restrict__ q, const float* __restrict__ k,
    const float* __restrict__ v, float* __restrict__ ctx)
{
    int bi = blockIdx.x;
    int qt = bi & 31;
    int bh = bi >> 5;
    int h = bh & (HH-1);
    int b = bh >> 2;
    int tid = threadIdx.x;
    int qo = tid >> 4;
    int c  = tid & 15;

    __shared__ float Qs[QT][68];
    __shared__ float Kt[64][64];
    __shared__ float Vs[64][68];
    __shared__ float Ps[QT][68];

    {
        const float* qp = q + ((size_t)(b*SS + qt*QT + qo)*DD) + h*DHH + c*4;
        *(float4*)&Qs[qo][c*4] = *(const float4*)qp;
    }
    float O0=0.f, O1=0.f, O2=0.f, O3=0.f;
    float mreg = -3.4e38f, lreg = 0.f;

    for (int t = 0; t < 8; ++t) {
        if (t) __syncthreads();
        #pragma unroll
        for (int e = 0; e < 4; ++e) {
            int lin = e*256 + tid;
            int kr = lin & 63;
            int c4 = lin >> 6;
            const float* kp = k + ((size_t)(b*SS + t*64 + kr)*DD) + h*DHH + c4*4;
            float4 kv = *(const float4*)kp;
            Kt[c4*4+0][kr] = kv.x;
            Kt[c4*4+1][kr] = kv.y;
            Kt[c4*4+2][kr] = kv.z;
            Kt[c4*4+3][kr] = kv.w;
            int vr = lin >> 4;
            int vc = lin & 15;
            const float* vp = v + ((size_t)(b*SS + t*64 + vr)*DD) + h*DHH + vc*4;
            *(float4*)&Vs[vr][vc*4] = *(const float4*)vp;
        }
        __syncthreads();
        float s0=0.f, s1=0.f, s2=0.f, s3=0.f;
        #pragma unroll 8
        for (int d = 0; d < 64; ++d) {
            float qv = Qs[qo][d];
            float4 kv = *(const float4*)&Kt[d][c*4];
            s0 = fmaf(qv, kv.x, s0);
            s1 = fmaf(qv, kv.y, s1);
            s2 = fmaf(qv, kv.z, s2);
            s3 = fmaf(qv, kv.w, s3);
        }
        s0 *= 0.125f; s1 *= 0.125f; s2 *= 0.125f; s3 *= 0.125f;
        float mx = fmaxf(fmaxf(s0, s1), fmaxf(s2, s3));
        #pragma unroll
        for (int mk = 1; mk <= 8; mk <<= 1)
            mx = fmaxf(mx, __shfl_xor(mx, mk));
        float mnew = fmaxf(mreg, mx);
        float scl = __expf(mreg - mnew);
        float e0 = __expf(s0 - mnew), e1 = __expf(s1 - mnew),
              e2 = __expf(s2 - mnew), e3 = __expf(s3 - mnew);
        float esum = e0 + e1 + e2 + e3;
        #pragma unroll
        for (int mk = 1; mk <= 8; mk <<= 1)
            esum += __shfl_xor(esum, mk);
        lreg = lreg * scl + esum;
        mreg = mnew;
        float4 pw; pw.x = e0; pw.y = e1; pw.z = e2; pw.w = e3;
        *(float4*)&Ps[qo][c*4] = pw;
        __syncthreads();
        O0 *= scl; O1 *= scl; O2 *= scl; O3 *= scl;
        #pragma unroll 8
        for (int kk = 0; kk < 64; ++kk) {
            float pv = Ps[qo][kk];
            float4 vv = *(const float4*)&Vs[kk][c*4];
            O0 = fmaf(pv, vv.x, O0);
            O1 = fmaf(pv, vv.y, O1);
            O2 = fmaf(pv, vv.z, O2);
            O3 = fmaf(pv, vv.w, O3);
        }
    }
    float linv = 1.0f / lreg;
    float4 o4; o4.x = O0*linv; o4.y = O1*linv; o4.z = O2*linv; o4.w = O3*linv;
    *(float4*)(ctx + ((size_t)(b*SS + qt*QT + qo)*DD) + h*DHH + c*4) = o4;
}

// ---------------------------------------------------------------------------
// Fused per-token kernel: route (path softmax + top-16) -> interaction FFN
// (agg stays in registers) -> pattern select (top-4, comb, bins).
// ---------------------------------------------------------------------------
__global__ __launch_bounds__(256) void token_kernel(
    const float* __restrict__ n1, const float* __restrict__ ctx,
    const float* __restrict__ Wpath, const float* __restrict__ bpath,
    const float* __restrict__ ts, const float* __restrict__ cs,
    const float* __restrict__ neurons,
    const float* __restrict__ nqa, const float* __restrict__ nka,
    const float* __restrict__ nva,
    const float* __restrict__ n2p, const float* __restrict__ PQ,
    float* __restrict__ comb_out, float* __restrict__ tpwg,
    int* __restrict__ binc, int* __restrict__ bine,
    float* __restrict__ out_idx)
{
    int t = blockIdx.x, tid = threadIdx.x;
    int wv = tid >> 6;

    __shared__ float sc[NN];
    __shared__ float pw0[4], pw1[4];
    __shared__ float w0s, w1s;
    __shared__ float wvv[4]; __shared__ int wvi[4];
    __shared__ float selv[KK]; __shared__ int seli[KK];
    __shared__ float tw[KK];
    __shared__ float nq[KK][DD+1];
    __shared__ float nk[KK][DD+1];
    __shared__ float nv[KK][DD+1];
    __shared__ float ps[HH][KK][KK];
    __shared__ float mix[DD];
    __shared__ float psp[8][33];
    __shared__ float pts[PP];
    __shared__ int tpi[KPP];

    float a = n1[t*DD+tid], c = ctx[t*DD+tid];

    // ---- phase 1: path weights ----
    {
        float r0 = a * Wpath[tid*2+0] + c * Wpath[(DD+tid)*2+0];
        float r1 = a * Wpath[tid*2+1] + c * Wpath[(DD+tid)*2+1];
        #pragma unroll
        for (int off = 1; off < 64; off <<= 1) {
            r0 += __shfl_xor(r0, off);
            r1 += __shfl_xor(r1, off);
        }
        if ((tid & 63) == 0) { pw0[wv] = r0; pw1[wv] = r1; }
    }
    __syncthreads();
    if (tid == 0) {
        float l0 = pw0[0]+pw0[1]+pw0[2]+pw0[3] + bpath[0];
        float l1 = pw1[0]+pw1[1]+pw1[2]+pw1[3] + bpath[1];
        float mm = fmaxf(l0, l1);
        float e0 = expf(l0-mm), e1 = expf(l1-mm);
        float is = 1.0f/(e0+e1);
        w0s = e0*is; w1s = e1*is;
    }
    __syncthreads();
    // ---- phase 2: score mix + top-16 ----
    {
        float w0 = w0s, w1 = w1s;
        sc[tid]     = w0*ts[t*NN+tid]     + w1*cs[t*NN+tid];
        sc[tid+256] = w0*ts[t*NN+tid+256] + w1*cs[t*NN+tid+256];
    }
    __syncthreads();
    for (int it = 0; it < KK; ++it) {
        float v0 = sc[tid], v1 = sc[tid+256];
        float bv; int bi;
        if (v0 >= v1) { bv = v0; bi = tid; } else { bv = v1; bi = tid+256; }
        #pragma unroll
        for (int off = 1; off < 64; off <<= 1) {
            float ov = __shfl_xor(bv, off);
            int   oi = __shfl_xor(bi, off);
            if (ov > bv || (ov == bv && oi < bi)) { bv = ov; bi = oi; }
        }
        if ((tid & 63) == 0) { wvv[wv] = bv; wvi[wv] = bi; }
        __syncthreads();
        if (tid == 0) {
            float fv = wvv[0]; int fi = wvi[0];
            #pragma unroll
            for (int w = 1; w < 4; ++w) {
                float ov = wvv[w]; int oi = wvi[w];
                if (ov > fv || (ov == fv && oi < fi)) { fv = ov; fi = oi; }
            }
            selv[it] = fv; seli[it] = fi; sc[fi] = -3.4e38f;
        }
        __syncthreads();
    }
    if (tid == 0) {
        float mx = selv[0];
        float e[KK]; float sum = 0.f;
        for (int i = 0; i < KK; ++i) { e[i] = expf(selv[i]-mx); sum += e[i]; }
        float is = 1.0f/sum;
        for (int i = 0; i < KK; ++i) {
            tw[i] = e[i]*is;
            out_idx[t*KK+i] = (float)seli[i];
        }
    }
    __syncthreads();

    // ---- phase 3: interaction FFN (gather projections, KxK attn, gate) ----
    for (int i = 0; i < KK; ++i) {
        int idx = seli[i];
        nq[i][tid] = nqa[idx*DD+tid];
        nk[i][tid] = nka[idx*DD+tid];
        nv[i][tid] = nva[idx*DD+tid];
    }
    __syncthreads();
    #pragma unroll
    for (int r = 0; r < 4; ++r) {
        int lin = r*256 + tid;         // (h,i,j)
        int j = lin & 15, i = (lin >> 4) & 15, h = lin >> 8;
        const float* qp = &nq[i][h*DHH];
        const float* kp = &nk[j][h*DHH];
        float acc = 0.f;
        #pragma unroll 8
        for (int d = 0; d < DHH; ++d) acc = fmaf(qp[d], kp[d], acc);
        ps[h][i][j] = acc * 0.125f;
    }
    __syncthreads();
    if (tid < 64) {
        int h = tid >> 4, i = tid & 15;
        float mx = -3.4e38f;
        for (int j = 0; j < KK; ++j) mx = fmaxf(mx, ps[h][i][j]);
        float sum = 0.f;
        for (int j = 0; j < KK; ++j) { float e = expf(ps[h][i][j]-mx); ps[h][i][j] = e; sum += e; }
        float is = 1.0f/sum;
        for (int j = 0; j < KK; ++j) ps[h][i][j] *= is;
    }
    __syncthreads();
    float agg = 0.f;
    {
        int d = tid, h = d >> 6;
        for (int i = 0; i < KK; ++i) {
            float g = 0.f;
            #pragma unroll
            for (int j = 0; j < KK; ++j) g = fmaf(ps[h][i][j], nv[j][d], g);
            agg += tw[i] * neurons[seli[i]*DD + d] * g;
        }
    }

    // ---- phase 4: pattern select ----
    mix[tid] = 0.03125f * agg + 0.5f * c;   // 0.5/sqrt(256) = 0.03125
    float cb = n2p[t*DD+tid] + agg;
    comb_out[t*DD+tid] = cb;
    __syncthreads();
    {
        int p = tid & 31, g = tid >> 5;
        const float* pq = PQ + p*DD + g*32;
        const float* mp = mix + g*32;
        float acc = 0.f;
        #pragma unroll
        for (int d = 0; d < 32; ++d) acc = fmaf(mp[d], pq[d], acc);
        psp[g][p] = acc;
    }
    __syncthreads();
    if (tid < PP) {
        float s = 0.f;
        #pragma unroll
        for (int g = 0; g < 8; ++g) s += psp[g][tid];
        pts[tid] = s;
    }
    __syncthreads();
    if (tid == 0) {
        float vals[KPP];
        #pragma unroll
        for (int it = 0; it < KPP; ++it) {
            float bv = -3.4e38f; int bi = 0;
            for (int p = 0; p < PP; ++p) { float v = pts[p]; if (v > bv) { bv = v; bi = p; } }
            vals[it] = bv; tpi[it] = bi; pts[bi] = -3.4e38f;
        }
        float mx = vals[0];
        float e0 = expf(vals[0]-mx), e1 = expf(vals[1]-mx),
              e2 = expf(vals[2]-mx), e3 = expf(vals[3]-mx);
        float is = 1.0f/(e0+e1+e2+e3);
        tpwg[t*4+0]=e0*is; tpwg[t*4+1]=e1*is; tpwg[t*4+2]=e2*is; tpwg[t*4+3]=e3*is;
    }
    __syncthreads();
    if (tid < KPP) {
        int p = tpi[tid];
        int slot = atomicAdd(&binc[p], 1);
        bine[p*TT + slot] = (t << 2) | tid;
    }
}

// ---------------------------------------------------------------------------
// LoRA mid: grid (PP, 8). A read straight from L2 (hot, 512KB/pattern);
// LDS only holds 16 comb rows -> 8 blocks/CU. Thread = (entry, 4 r).
// Writes hmid_g[e][64] (tpw folded), e = (t<<2)|kp.
// ---------------------------------------------------------------------------
__global__ __launch_bounds__(256) void lora_mid(
    const float* __restrict__ comb, const float* __restrict__ tpwg,
    const int* __restrict__ bin_count, const int* __restrict__ bin_entry,
    const float* __restrict__ Aup, float* __restrict__ hmid_g)
{
    int p = blockIdx.x, sub = blockIdx.y;
    int cnt = bin_count[p];
    if (sub * 16 >= cnt) return;
    int tid = threadIdx.x;

    __shared__ float combs[16][DD+4];
    __shared__ int es[16];

    const float* Ap = Aup + (size_t)p*(DD*RR);

    for (int base = sub*16; base < cnt; base += 8*16) {
        int nt = cnt - base; if (nt > 16) nt = 16;
        __syncthreads();
        if (tid < 16) es[tid] = (tid < nt) ? bin_entry[p*TT + base + tid] : -1;
        __syncthreads();
        #pragma unroll
        for (int i = 0; i < 16; ++i) {
            int e = es[i];
            combs[i][tid] = (e >= 0) ? comb[(size_t)(e >> 2)*DD + tid] : 0.f;
        }
        __syncthreads();

        int i = tid >> 4, rg = tid & 15;
        float a0=0.f, a1=0.f, a2=0.f, a3=0.f;
        #pragma unroll 8
        for (int d = 0; d < DD; ++d) {
            float cv = combs[i][d];
            float4 av = *(const float4*)&Ap[(size_t)d*RR + rg*4];
            a0 = fmaf(cv, av.x, a0);
            a1 = fmaf(cv, av.y, a1);
            a2 = fmaf(cv, av.z, a2);
            a3 = fmaf(cv, av.w, a3);
        }
        int e = es[i];
        if (e >= 0) {
            float w = tpwg[e];
            float4 o; o.x = a0*w; o.y = a1*w; o.z = a2*w; o.w = a3*w;
            *(float4*)&hmid_g[(size_t)e*RR + rg*4] = o;
        }
    }
}

// ---------------------------------------------------------------------------
// LoRA apply: grid (PP, FFD/128, 16). Block = (pattern, ff-tile, 64-entry
// chunk). B tile (32KB) + transposed hm tile (17KB) in LDS; inner loop is
// 3x ds_read_b128 (2 broadcast) per 32 FMA -> VALU-bound. ~3 blocks/CU.
// ---------------------------------------------------------------------------
__global__ __launch_bounds__(256) void lora_apply(
    const int* __restrict__ bin_count, const int* __restrict__ bin_entry,
    const float* __restrict__ hmid_g, const float* __restrict__ Bup,
    float* __restrict__ hpat4)
{
    int p = blockIdx.x, ff0 = blockIdx.y * 128;
    int base = blockIdx.z * 64;
    int cnt = bin_count[p];
    if (base >= cnt) return;
    int nt = cnt - base; if (nt > 64) nt = 64;
    int tid = threadIdx.x;

    __shared__ float Bs[RR][132];      // 33.8 KB
    __shared__ float hmT[RR][68];      // 17.4 KB, transposed: hmT[r][entry]
    __shared__ int es[64];

    // stage B tile (2048 float4)
    const float* Bp = Bup + (size_t)p*(RR*FFD) + ff0;
    #pragma unroll
    for (int e = 0; e < 8; ++e) {
        int lin = e*256 + tid;
        int r = lin >> 5, cg = lin & 31;
        *(float4*)&Bs[r][cg*4] = *(const float4*)&Bp[(size_t)r*FFD + cg*4];
    }
    if (tid < 64) es[tid] = (tid < nt) ? bin_entry[p*TT + base + tid] : -1;
    __syncthreads();
    // stage hm transposed (64 entries x 64 r)
    #pragma unroll
    for (int e = 0; e < 4; ++e) {
        int lin = e*256 + tid;         // 1024 float4
        int i = lin >> 4, rg = lin & 15;
        int ei = es[i];
        float4 hv = make_float4(0.f,0.f,0.f,0.f);
        if (ei >= 0) hv = *(const float4*)&hmid_g[(size_t)ei*RR + rg*4];
        hmT[rg*4+0][i] = hv.x;
        hmT[rg*4+1][i] = hv.y;
        hmT[rg*4+2][i] = hv.z;
        hmT[rg*4+3][i] = hv.w;
    }
    __syncthreads();

    int eg = tid >> 5, cg = tid & 31;  // 8 entries x 4 cols per thread
    float4 acc[8];
    #pragma unroll
    for (int j = 0; j < 8; ++j) acc[j] = make_float4(0.f,0.f,0.f,0.f);
    #pragma unroll 4
    for (int r = 0; r < RR; ++r) {
        float4 b  = *(const float4*)&Bs[r][cg*4];
        float4 h0 = *(const float4*)&hmT[r][eg*8];
        float4 h1 = *(const float4*)&hmT[r][eg*8+4];
        acc[0].x = fmaf(h0.x, b.x, acc[0].x); acc[0].y = fmaf(h0.x, b.y, acc[0].y);
        acc[0].z = fmaf(h0.x, b.z, acc[0].z); acc[0].w = fmaf(h0.x, b.w, acc[0].w);
        acc[1].x = fmaf(h0.y, b.x, acc[1].x); acc[1].y = fmaf(h0.y, b.y, acc[1].y);
        acc[1].z = fmaf(h0.y, b.z, acc[1].z); acc[1].w = fmaf(h0.y, b.w, acc[1].w);
        acc[2].x = fmaf(h0.z, b.x, acc[2].x); acc[2].y = fmaf(h0.z, b.y, acc[2].y);
        acc[2].z = fmaf(h0.z, b.z, acc[2].z); acc[2].w = fmaf(h0.z, b.w, acc[2].w);
        acc[3].x = fmaf(h0.w, b.x, acc[3].x); acc[3].y = fmaf(h0.w, b.y, acc[3].y);
        acc[3].z = fmaf(h0.w, b.z, acc[3].z); acc[3].w = fmaf(h0.w, b.w, acc[3].w);
        acc[4].x = fmaf(h1.x, b.x, acc[4].x); acc[4].y = fmaf(h1.x, b.y, acc[4].y);
        acc[4].z = fmaf(h1.x, b.z, acc[4].z); acc[4].w = fmaf(h1.x, b.w, acc[4].w);
        acc[5].x = fmaf(h1.y, b.x, acc[5].x); acc[5].y = fmaf(h1.y, b.y, acc[5].y);
        acc[5].z = fmaf(h1.y, b.z, acc[5].z); acc[5].w = fmaf(h1.y, b.w, acc[5].w);
        acc[6].x = fmaf(h1.z, b.x, acc[6].x); acc[6].y = fmaf(h1.z, b.y, acc[6].y);
        acc[6].z = fmaf(h1.z, b.z, acc[6].z); acc[6].w = fmaf(h1.z, b.w, acc[6].w);
        acc[7].x = fmaf(h1.w, b.x, acc[7].x); acc[7].y = fmaf(h1.w, b.y, acc[7].y);
        acc[7].z = fmaf(h1.w, b.z, acc[7].z); acc[7].w = fmaf(h1.w, b.w, acc[7].w);
    }
    #pragma unroll
    for (int j = 0; j < 8; ++j) {
        int e = es[eg*8+j];
        if (e >= 0) {
            int t = e >> 2, kp = e & 3;
            *(float4*)&hpat4[(size_t)kp*(TT*FFD) + (size_t)t*FFD + ff0 + cg*4] = acc[j];
        }
    }
}

// ---------------------------------------------------------------------------
extern "C" void kernel_launch(void* const* d_in, const int* in_sizes, int n_in,
                              void* d_out, int out_size, void* d_ws, size_t ws_size,
                              hipStream_t stream)
{
    const float* x        = (const float*)d_in[0];
    const float* g1       = (const float*)d_in[1];
    const float* b1       = (const float*)d_in[2];
    const float* g2       = (const float*)d_in[3];
    const float* b2       = (const float*)d_in[4];
    const float* Wq       = (const float*)d_in[5];
    const float* bq       = (const float*)d_in[6];
    const float* Wk       = (const float*)d_in[7];
    const float* bk       = (const float*)d_in[8];
    const float* Wv       = (const float*)d_in[9];
    const float* bv       = (const float*)d_in[10];
    const float* Wpath    = (const float*)d_in[11];
    const float* bpath    = (const float*)d_in[12];
    const float* neurons  = (const float*)d_in[13];
    const float* Wnq      = (const float*)d_in[14];
    const float* bnq      = (const float*)d_in[15];
    const float* Wnk      = (const float*)d_in[16];
    const float* bnk      = (const float*)d_in[17];
    const float* Wnv      = (const float*)d_in[18];
    const float* bnv      = (const float*)d_in[19];
    const float* PQ       = (const float*)d_in[20];
    const float* Aup      = (const float*)d_in[21];
    const float* Bup      = (const float*)d_in[22];
    const float* Wub      = (const float*)d_in[23];
    const float* bub      = (const float*)d_in[24];
    const float* Wd       = (const float*)d_in[25];
    const float* bd       = (const float*)d_in[26];

    float* out0    = (float*)d_out;              // [B,S,D] residual output
    float* out_idx = out0 + (size_t)TT*DD;       // [B,S,K] indices (as float)

    // workspace carve-up (floats)
    float* ws = (float*)d_ws;
    float* n1    = ws; ws += TT*DD;
    float* n2    = ws; ws += TT*DD;
    float* qb    = ws; ws += TT*DD;
    float* kb    = ws; ws += TT*DD;
    float* vb    = ws; ws += TT*DD;
    float* ctx   = ws; ws += TT*DD;
    float* ts    = ws; ws += TT*NN;
    float* cs    = ws; ws += TT*NN;
    float* nqa   = ws; ws += NN*DD;
    float* nka   = ws; ws += NN*DD;
    float* nva   = ws; ws += NN*DD;
    float* comb  = ws; ws += TT*DD;
    float* hpat4 = ws; ws += 4*TT*FFD;           // 4 slices (one per kp)
    float* hb    = ws; ws += TT*FFD;
    float* part  = ws; ws += 4*TT*DD;            // split-K partials for Wd
    float* hmidg = ws; ws += 4*TT*RR;            // hmid per entry e=(t<<2)|kp
    float* tpwg  = ws; ws += TT*KPP;
    int*   binc  = (int*)ws; ws += 32;
    int*   bine  = (int*)ws; ws += 32*TT;

    dim3 blk(256);

    // 1. LayerNorms (+ zero bin counters)
    ln_kernel<<<TT, blk, 0, stream>>>(x, g1, b1, g2, b2, n1, n2, binc);

    // 2. QKV projections batched (M=1024,N=256,K=256, z=3)
    {
        GemmSet sq{n1, Wq, bq, qb, 0}, sk{n1, Wk, bk, kb, 0}, sv{n1, Wv, bv, vb, 0};
        gemm3_kernel<<<dim3(DD/64, TT/64, 3), blk, 0, stream>>>(sq, sk, sv, TT, DD, DD, 0);
    }

    // 3. Neuron projections batched (M=512,N=256,K=256, z=3); nv -> sigmoid
    {
        GemmSet s0{neurons, Wnq, bnq, nqa, 0}, s1{neurons, Wnk, bnk, nka, 0},
                s2{neurons, Wnv, bnv, nva, 1};
        gemm3_kernel<<<dim3(DD/64, NN/64, 3), blk, 0, stream>>>(s0, s1, s2, NN, DD, DD, 0);
    }

    // 4. Attention -> context  (flash-style, 256 blocks)
    attn_kernel<<<BB*HH*(SS/QT), blk, 0, stream>>>(qb, kb, vb, ctx);

    // 5. token/context scores vs neurons^T (M=1024,N=512,K=256, transB, z=2)
    {
        GemmSet s0{n1, neurons, nullptr, ts, 0}, s1{ctx, neurons, nullptr, cs, 0};
        gemm3_kernel<<<dim3(NN/64, TT/64, 2), blk, 0, stream>>>(s0, s1, s1, TT, NN, DD, 1);
    }

    // 6. fused per-token: route -> interaction FFN -> pattern select
    token_kernel<<<TT, blk, 0, stream>>>(n1, ctx, Wpath, bpath, ts, cs,
                                         neurons, nqa, nka, nva, n2, PQ,
                                         comb, tpwg, binc, bine, out_idx);

    // 7. LoRA mid (grouped by pattern) -> hmid_g
    lora_mid<<<dim3(PP, 8), blk, 0, stream>>>(comb, tpwg, binc, bine, Aup, hmidg);

    // 8. LoRA apply (grouped by pattern, entry-chunked) -> hpat4 slices
    lora_apply<<<dim3(PP, FFD/128, 16), blk, 0, stream>>>(binc, bine, hmidg, Bup, hpat4);

    // 9. h = gelu(0.1*(comb@Wub+bub) + 0.9*sum(hpat4))   (M=1024,N=1024,K=256)
    gemm_kernel<<<dim3(FFD/64, TT/64), blk, 0, stream>>>(comb, Wub, bub, hpat4, hb, TT, FFD, DD, 0, 2);

    // 10. out = x + h@Wd + bd  via split-K(4) + combine  (M=1024,N=256,K=1024)
    gemm_splitk_kernel<<<dim3(DD/64, TT/64, 4), blk, 0, stream>>>(hb, Wd, part, TT, DD, FFD, FFD/4);
    combine_wd_kernel<<<TT*DD/256, blk, 0, stream>>>(part, x, bd, out0);
}

// Round 8
// 346.691 us; speedup vs baseline: 1.1946x; 1.1635x over previous
//
#include <hip/hip_runtime.h>
#include <hip/hip_bf16.h>
#include <math.h>

// Problem dims (fixed)
#define BB 2
#define SS 512
#define DD 256
#define FFD 1024
#define HH 4
#define NN 512
#define PP 32
#define KK 16
#define KPP 4
#define RR 64
#define DHH 64
#define TT (BB*SS)   // 1024 tokens
#define QT 16        // attn queries per block

// ---------------------------------------------------------------------------
// LayerNorm (+ zero the 32 bin counters from block 0). One block per token.
// ---------------------------------------------------------------------------
__global__ __launch_bounds__(256) void ln_kernel(
    const float* __restrict__ x,
    const float* __restrict__ g1, const float* __restrict__ b1,
    const float* __restrict__ g2, const float* __restrict__ b2,
    float* __restrict__ n1, float* __restrict__ n2,
    int* __restrict__ binc)
{
    int t = blockIdx.x;
    int d = threadIdx.x;
    if (t == 0 && d < 32) binc[d] = 0;
    __shared__ float red[256];
    float v = x[t*DD + d];
    red[d] = v; __syncthreads();
    for (int s = 128; s > 0; s >>= 1) { if (d < s) red[d] += red[d+s]; __syncthreads(); }
    float mu = red[0] * (1.0f/DD);
    __syncthreads();
    float dv = v - mu;
    red[d] = dv*dv; __syncthreads();
    for (int s = 128; s > 0; s >>= 1) { if (d < s) red[d] += red[d+s]; __syncthreads(); }
    float var = red[0] * (1.0f/DD);
    float r = 1.0f / sqrtf(var + 1e-5f);
    n1[t*DD+d] = dv*r*g1[d] + b1[d];
    n2[t*DD+d] = dv*r*g2[d] + b2[d];
}

// ---------------------------------------------------------------------------
// GEMM body: 64x64 tile, BK=32, 256 threads, register double-buffering.
//   mode 0: none; 1: sigmoid; 2: gelu(0.1*val+0.9*sum4slices(extra)); 3: val+extra
// ---------------------------------------------------------------------------
__device__ __forceinline__ void gemm_body(
    const float* __restrict__ A, const float* __restrict__ Bm,
    const float* __restrict__ bias, const float* __restrict__ extra,
    float* __restrict__ C, int M, int Nn, int Kk, int transB, int mode,
    int k0off, int kLen)
{
    __shared__ float As[2][32][68];   // As[buf][k][m] (transposed)
    __shared__ float Bs[2][32][68];   // Bs[buf][k][n]
    int bm = blockIdx.y * 64;
    int bn = blockIdx.x * 64;
    int tid = threadIdx.x;
    int tx = tid & 15, ty = tid >> 4;

    float4 pa[2], pb[2];

    #define LOAD_A(kbase) { \
        _Pragma("unroll") \
        for (int e = 0; e < 2; ++e) { \
            int r = e*32 + (tid>>3); int c4 = tid & 7; \
            pa[e] = *(const float4*)&A[(size_t)(bm + r)*Kk + (kbase) + c4*4]; \
        } }
    #define STORE_A(buf) { \
        _Pragma("unroll") \
        for (int e = 0; e < 2; ++e) { \
            int r = e*32 + (tid>>3); int c4 = tid & 7; \
            As[buf][c4*4+0][r] = pa[e].x; \
            As[buf][c4*4+1][r] = pa[e].y; \
            As[buf][c4*4+2][r] = pa[e].z; \
            As[buf][c4*4+3][r] = pa[e].w; \
        } }
    #define LOAD_B(kbase) { \
        if (transB == 0) { \
            _Pragma("unroll") \
            for (int e = 0; e < 2; ++e) { \
                int c = e*16 + (tid>>4); int n4 = tid & 15; \
                pb[e] = *(const float4*)&Bm[(size_t)((kbase) + c)*Nn + bn + n4*4]; \
            } \
        } else { \
            _Pragma("unroll") \
            for (int e = 0; e < 2; ++e) { \
                int r = e*32 + (tid>>3); int k4 = tid & 7; \
                pb[e] = *(const float4*)&Bm[(size_t)(bn + r)*Kk + (kbase) + k4*4]; \
            } \
        } }
    #define STORE_B(buf) { \
        if (transB == 0) { \
            _Pragma("unroll") \
            for (int e = 0; e < 2; ++e) { \
                int c = e*16 + (tid>>4); int n4 = tid & 15; \
                *(float4*)&Bs[buf][c][n4*4] = pb[e]; \
            } \
        } else { \
            _Pragma("unroll") \
            for (int e = 0; e < 2; ++e) { \
                int r = e*32 + (tid>>3); int k4 = tid & 7; \
                Bs[buf][k4*4+0][r] = pb[e].x; \
                Bs[buf][k4*4+1][r] = pb[e].y; \
                Bs[buf][k4*4+2][r] = pb[e].z; \
                Bs[buf][k4*4+3][r] = pb[e].w; \
            } \
        } }

    float acc[4][4] = {};
    int nk = kLen >> 5;   // BK=32

    LOAD_A(k0off); LOAD_B(k0off);
    STORE_A(0); STORE_B(0);
    __syncthreads();

    for (int kt = 0; kt < nk; ++kt) {
        int cur = kt & 1;
        if (kt + 1 < nk) { LOAD_A(k0off + (kt+1)*32); LOAD_B(k0off + (kt+1)*32); }
        #pragma unroll
        for (int kk = 0; kk < 32; ++kk) {
            float4 av = *(const float4*)&As[cur][kk][ty*4];
            float4 bv = *(const float4*)&Bs[cur][kk][tx*4];
            acc[0][0] = fmaf(av.x, bv.x, acc[0][0]);
            acc[0][1] = fmaf(av.x, bv.y, acc[0][1]);
            acc[0][2] = fmaf(av.x, bv.z, acc[0][2]);
            acc[0][3] = fmaf(av.x, bv.w, acc[0][3]);
            acc[1][0] = fmaf(av.y, bv.x, acc[1][0]);
            acc[1][1] = fmaf(av.y, bv.y, acc[1][1]);
            acc[1][2] = fmaf(av.y, bv.z, acc[1][2]);
            acc[1][3] = fmaf(av.y, bv.w, acc[1][3]);
            acc[2][0] = fmaf(av.z, bv.x, acc[2][0]);
            acc[2][1] = fmaf(av.z, bv.y, acc[2][1]);
            acc[2][2] = fmaf(av.z, bv.z, acc[2][2]);
            acc[2][3] = fmaf(av.z, bv.w, acc[2][3]);
            acc[3][0] = fmaf(av.w, bv.x, acc[3][0]);
            acc[3][1] = fmaf(av.w, bv.y, acc[3][1]);
            acc[3][2] = fmaf(av.w, bv.z, acc[3][2]);
            acc[3][3] = fmaf(av.w, bv.w, acc[3][3]);
        }
        if (kt + 1 < nk) {
            STORE_A(cur^1); STORE_B(cur^1);
            __syncthreads();
        }
    }

    #pragma unroll
    for (int i = 0; i < 4; ++i) {
        int m = bm + ty*4 + i;
        #pragma unroll
        for (int j = 0; j < 4; ++j) {
            int n = bn + tx*4 + j;
            float val = acc[i][j] + (bias ? bias[n] : 0.0f);
            if (mode == 1) {
                val = 1.0f / (1.0f + expf(-val));
            } else if (mode == 2) {
                size_t idx = (size_t)m*Nn + n;
                float hp = extra[idx] + extra[idx + (size_t)TT*FFD]
                         + extra[idx + 2*(size_t)TT*FFD] + extra[idx + 3*(size_t)TT*FFD];
                float z = 0.1f*val + 0.9f*hp;
                val = 0.5f*z*(1.0f + erff(z*0.70710678118654752f));
            } else if (mode == 3) {
                val = val + extra[(size_t)m*Nn+n];
            }
            C[(size_t)m*Nn + n] = val;
        }
    }
    #undef LOAD_A
    #undef STORE_A
    #undef LOAD_B
    #undef STORE_B
}

__global__ __launch_bounds__(256) void gemm_kernel(
    const float* __restrict__ A, const float* __restrict__ Bm,
    const float* __restrict__ bias, const float* __restrict__ extra,
    float* __restrict__ C, int M, int Nn, int Kk, int transB, int mode)
{
    gemm_body(A, Bm, bias, extra, C, M, Nn, Kk, transB, mode, 0, Kk);
}

struct GemmSet { const float* A; const float* B; const float* bias; float* C; int mode; int M; };

__global__ __launch_bounds__(256) void gemm2_kernel(
    GemmSet s0, GemmSet s1, int Nn, int Kk, int transB)
{
    GemmSet s = (blockIdx.z == 0) ? s0 : s1;
    if ((int)blockIdx.y * 64 >= s.M) return;
    gemm_body(s.A, s.B, s.bias, nullptr, s.C, s.M, Nn, Kk, transB, s.mode, 0, Kk);
}

__global__ __launch_bounds__(256) void gemm6_kernel(
    GemmSet s0, GemmSet s1, GemmSet s2, GemmSet s3, GemmSet s4, GemmSet s5,
    int Nn, int Kk, int transB)
{
    GemmSet s;
    switch (blockIdx.z) {
        case 0: s = s0; break;
        case 1: s = s1; break;
        case 2: s = s2; break;
        case 3: s = s3; break;
        case 4: s = s4; break;
        default: s = s5; break;
    }
    if ((int)blockIdx.y * 64 >= s.M) return;
    gemm_body(s.A, s.B, s.bias, nullptr, s.C, s.M, Nn, Kk, transB, s.mode, 0, Kk);
}

__global__ __launch_bounds__(256) void gemm_splitk_kernel(
    const float* __restrict__ A, const float* __restrict__ Bm,
    float* __restrict__ Cpart, int M, int Nn, int Kk, int kPerSplit)
{
    int sk = blockIdx.z;
    float* Cp = Cpart + (size_t)sk * M * Nn;
    gemm_body(A, Bm, nullptr, nullptr, Cp, M, Nn, Kk, 0, 0, sk*kPerSplit, kPerSplit);
}

__global__ __launch_bounds__(256) void combine_wd_kernel(
    const float* __restrict__ part, const float* __restrict__ x,
    const float* __restrict__ bd, float* __restrict__ out)
{
    int i = blockIdx.x*256 + threadIdx.x;
    int d = i & (DD-1);
    float s = x[i] + bd[d];
    s += part[i] + part[i + TT*DD] + part[i + 2*TT*DD] + part[i + 3*TT*DD];
    out[i] = s;
}

// ---------------------------------------------------------------------------
// Flash-style attention: block = (b, h, 16-query tile). 256 blocks, 256 thr.
// ---------------------------------------------------------------------------
__global__ __launch_bounds__(256) void attn_kernel(
    const float* __restrict__ q, const float* __restrict__ k,
    const float* __restrict__ v, float* __restrict__ ctx)
{
    int bi = blockIdx.x;
    int qt = bi & 31;
    int bh = bi >> 5;
    int h = bh & (HH-1);
    int b = bh >> 2;
    int tid = threadIdx.x;
    int qo = tid >> 4;
    int c  = tid & 15;

    __shared__ float Qs[QT][68];
    __shared__ float Kt[64][64];
    __shared__ float Vs[64][68];
    __shared__ float Ps[QT][68];

    {
        const float* qp = q + ((size_t)(b*SS + qt*QT + qo)*DD) + h*DHH + c*4;
        *(float4*)&Qs[qo][c*4] = *(const float4*)qp;
    }
    float O0=0.f, O1=0.f, O2=0.f, O3=0.f;
    float mreg = -3.4e38f, lreg = 0.f;

    for (int t = 0; t < 8; ++t) {
        if (t) __syncthreads();
        #pragma unroll
        for (int e = 0; e < 4; ++e) {
            int lin = e*256 + tid;
            int kr = lin & 63;
            int c4 = lin >> 6;
            const float* kp = k + ((size_t)(b*SS + t*64 + kr)*DD) + h*DHH + c4*4;
            float4 kv = *(const float4*)kp;
            Kt[c4*4+0][kr] = kv.x;
            Kt[c4*4+1][kr] = kv.y;
            Kt[c4*4+2][kr] = kv.z;
            Kt[c4*4+3][kr] = kv.w;
            int vr = lin >> 4;
            int vc = lin & 15;
            const float* vp = v + ((size_t)(b*SS + t*64 + vr)*DD) + h*DHH + vc*4;
            *(float4*)&Vs[vr][vc*4] = *(const float4*)vp;
        }
        __syncthreads();
        float s0=0.f, s1=0.f, s2=0.f, s3=0.f;
        #pragma unroll 8
        for (int d = 0; d < 64; ++d) {
            float qv = Qs[qo][d];
            float4 kv = *(const float4*)&Kt[d][c*4];
            s0 = fmaf(qv, kv.x, s0);
            s1 = fmaf(qv, kv.y, s1);
            s2 = fmaf(qv, kv.z, s2);
            s3 = fmaf(qv, kv.w, s3);
        }
        s0 *= 0.125f; s1 *= 0.125f; s2 *= 0.125f; s3 *= 0.125f;
        float mx = fmaxf(fmaxf(s0, s1), fmaxf(s2, s3));
        #pragma unroll
        for (int mk = 1; mk <= 8; mk <<= 1)
            mx = fmaxf(mx, __shfl_xor(mx, mk));
        float mnew = fmaxf(mreg, mx);
        float scl = __expf(mreg - mnew);
        float e0 = __expf(s0 - mnew), e1 = __expf(s1 - mnew),
              e2 = __expf(s2 - mnew), e3 = __expf(s3 - mnew);
        float esum = e0 + e1 + e2 + e3;
        #pragma unroll
        for (int mk = 1; mk <= 8; mk <<= 1)
            esum += __shfl_xor(esum, mk);
        lreg = lreg * scl + esum;
        mreg = mnew;
        float4 pw; pw.x = e0; pw.y = e1; pw.z = e2; pw.w = e3;
        *(float4*)&Ps[qo][c*4] = pw;
        __syncthreads();
        O0 *= scl; O1 *= scl; O2 *= scl; O3 *= scl;
        #pragma unroll 8
        for (int kk = 0; kk < 64; ++kk) {
            float pv = Ps[qo][kk];
            float4 vv = *(const float4*)&Vs[kk][c*4];
            O0 = fmaf(pv, vv.x, O0);
            O1 = fmaf(pv, vv.y, O1);
            O2 = fmaf(pv, vv.z, O2);
            O3 = fmaf(pv, vv.w, O3);
        }
    }
    float linv = 1.0f / lreg;
    float4 o4; o4.x = O0*linv; o4.y = O1*linv; o4.z = O2*linv; o4.w = O3*linv;
    *(float4*)(ctx + ((size_t)(b*SS + qt*QT + qo)*DD) + h*DHH + c*4) = o4;
}

// ---------------------------------------------------------------------------
// Fused per-token kernel: route (path softmax + top-16) -> interaction FFN
// (agg stays in registers) -> pattern select (top-4, comb, bins, tpi/tpw out).
// ---------------------------------------------------------------------------
__global__ __launch_bounds__(256) void token_kernel(
    const float* __restrict__ n1, const float* __restrict__ ctx,
    const float* __restrict__ Wpath, const float* __restrict__ bpath,
    const float* __restrict__ ts, const float* __restrict__ cs,
    const float* __restrict__ neurons,
    const float* __restrict__ nqa, const float* __restrict__ nka,
    const float* __restrict__ nva,
    const float* __restrict__ n2p, const float* __restrict__ PQ,
    float* __restrict__ comb_out, float* __restrict__ tpwg,
    int* __restrict__ tpib,
    int* __restrict__ binc, int* __restrict__ bine,
    float* __restrict__ out_idx)
{
    int t = blockIdx.x, tid = threadIdx.x;
    int wv = tid >> 6;

    __shared__ float sc[NN];
    __shared__ float pw0[4], pw1[4];
    __shared__ float w0s, w1s;
    __shared__ float wvv[4]; __shared__ int wvi[4];
    __shared__ float selv[KK]; __shared__ int seli[KK];
    __shared__ float tw[KK];
    __shared__ float nq[KK][DD+1];
    __shared__ float nk[KK][DD+1];
    __shared__ float nv[KK][DD+1];
    __shared__ float ps[HH][KK][KK];
    __shared__ float mix[DD];
    __shared__ float psp[8][33];
    __shared__ float pts[PP];
    __shared__ int tpi[KPP];

    float a = n1[t*DD+tid], c = ctx[t*DD+tid];

    // ---- phase 1: path weights ----
    {
        float r0 = a * Wpath[tid*2+0] + c * Wpath[(DD+tid)*2+0];
        float r1 = a * Wpath[tid*2+1] + c * Wpath[(DD+tid)*2+1];
        #pragma unroll
        for (int off = 1; off < 64; off <<= 1) {
            r0 += __shfl_xor(r0, off);
            r1 += __shfl_xor(r1, off);
        }
        if ((tid & 63) == 0) { pw0[wv] = r0; pw1[wv] = r1; }
    }
    __syncthreads();
    if (tid == 0) {
        float l0 = pw0[0]+pw0[1]+pw0[2]+pw0[3] + bpath[0];
        float l1 = pw1[0]+pw1[1]+pw1[2]+pw1[3] + bpath[1];
        float mm = fmaxf(l0, l1);
        float e0 = expf(l0-mm), e1 = expf(l1-mm);
        float is = 1.0f/(e0+e1);
        w0s = e0*is; w1s = e1*is;
    }
    __syncthreads();
    // ---- phase 2: score mix + top-16 ----
    {
        float w0 = w0s, w1 = w1s;
        sc[tid]     = w0*ts[t*NN+tid]     + w1*cs[t*NN+tid];
        sc[tid+256] = w0*ts[t*NN+tid+256] + w1*cs[t*NN+tid+256];
    }
    __syncthreads();
    for (int it = 0; it < KK; ++it) {
        float v0 = sc[tid], v1 = sc[tid+256];
        float bv; int bi;
        if (v0 >= v1) { bv = v0; bi = tid; } else { bv = v1; bi = tid+256; }
        #pragma unroll
        for (int off = 1; off < 64; off <<= 1) {
            float ov = __shfl_xor(bv, off);
            int   oi = __shfl_xor(bi, off);
            if (ov > bv || (ov == bv && oi < bi)) { bv = ov; bi = oi; }
        }
        if ((tid & 63) == 0) { wvv[wv] = bv; wvi[wv] = bi; }
        __syncthreads();
        if (tid == 0) {
            float fv = wvv[0]; int fi = wvi[0];
            #pragma unroll
            for (int w = 1; w < 4; ++w) {
                float ov = wvv[w]; int oi = wvi[w];
                if (ov > fv || (ov == fv && oi < fi)) { fv = ov; fi = oi; }
            }
            selv[it] = fv; seli[it] = fi; sc[fi] = -3.4e38f;
        }
        __syncthreads();
    }
    if (tid == 0) {
        float mx = selv[0];
        float e[KK]; float sum = 0.f;
        for (int i = 0; i < KK; ++i) { e[i] = expf(selv[i]-mx); sum += e[i]; }
        float is = 1.0f/sum;
        for (int i = 0; i < KK; ++i) {
            tw[i] = e[i]*is;
            out_idx[t*KK+i] = (float)seli[i];
        }
    }
    __syncthreads();

    // ---- phase 3: interaction FFN (gather projections, KxK attn, gate) ----
    for (int i = 0; i < KK; ++i) {
        int idx = seli[i];
        nq[i][tid] = nqa[idx*DD+tid];
        nk[i][tid] = nka[idx*DD+tid];
        nv[i][tid] = nva[idx*DD+tid];
    }
    __syncthreads();
    #pragma unroll
    for (int r = 0; r < 4; ++r) {
        int lin = r*256 + tid;         // (h,i,j)
        int j = lin & 15, i = (lin >> 4) & 15, h = lin >> 8;
        const float* qp = &nq[i][h*DHH];
        const float* kp = &nk[j][h*DHH];
        float acc = 0.f;
        #pragma unroll 8
        for (int d = 0; d < DHH; ++d) acc = fmaf(qp[d], kp[d], acc);
        ps[h][i][j] = acc * 0.125f;
    }
    __syncthreads();
    if (tid < 64) {
        int h = tid >> 4, i = tid & 15;
        float mx = -3.4e38f;
        for (int j = 0; j < KK; ++j) mx = fmaxf(mx, ps[h][i][j]);
        float sum = 0.f;
        for (int j = 0; j < KK; ++j) { float e = expf(ps[h][i][j]-mx); ps[h][i][j] = e; sum += e; }
        float is = 1.0f/sum;
        for (int j = 0; j < KK; ++j) ps[h][i][j] *= is;
    }
    __syncthreads();
    float agg = 0.f;
    {
        int d = tid, h = d >> 6;
        for (int i = 0; i < KK; ++i) {
            float g = 0.f;
            #pragma unroll
            for (int j = 0; j < KK; ++j) g = fmaf(ps[h][i][j], nv[j][d], g);
            agg += tw[i] * neurons[seli[i]*DD + d] * g;
        }
    }

    // ---- phase 4: pattern select ----
    mix[tid] = 0.03125f * agg + 0.5f * c;   // 0.5/sqrt(256) = 0.03125
    float cb = n2p[t*DD+tid] + agg;
    comb_out[t*DD+tid] = cb;
    __syncthreads();
    {
        int p = tid & 31, g = tid >> 5;
        const float* pq = PQ + p*DD + g*32;
        const float* mp = mix + g*32;
        float acc = 0.f;
        #pragma unroll
        for (int d = 0; d < 32; ++d) acc = fmaf(mp[d], pq[d], acc);
        psp[g][p] = acc;
    }
    __syncthreads();
    if (tid < PP) {
        float s = 0.f;
        #pragma unroll
        for (int g = 0; g < 8; ++g) s += psp[g][tid];
        pts[tid] = s;
    }
    __syncthreads();
    if (tid == 0) {
        float vals[KPP];
        #pragma unroll
        for (int it = 0; it < KPP; ++it) {
            float bv = -3.4e38f; int bi = 0;
            for (int p = 0; p < PP; ++p) { float v = pts[p]; if (v > bv) { bv = v; bi = p; } }
            vals[it] = bv; tpi[it] = bi; pts[bi] = -3.4e38f;
        }
        float mx = vals[0];
        float e0 = expf(vals[0]-mx), e1 = expf(vals[1]-mx),
              e2 = expf(vals[2]-mx), e3 = expf(vals[3]-mx);
        float is = 1.0f/(e0+e1+e2+e3);
        tpwg[t*4+0]=e0*is; tpwg[t*4+1]=e1*is; tpwg[t*4+2]=e2*is; tpwg[t*4+3]=e3*is;
    }
    __syncthreads();
    if (tid < KPP) {
        int p = tpi[tid];
        tpib[t*4+tid] = p;
        int slot = atomicAdd(&binc[p], 1);
        bine[p*TT + slot] = (t << 2) | tid;
    }
}

// ---------------------------------------------------------------------------
// hmid: block per token (1024 blocks, tiny LDS -> 8 blocks/CU, 32 waves/CU).
// Thread = (kp = tid>>6, r = tid&63). Per-wave A reads are 256B coalesced;
// TLP hides L2/L3 latency (the R7 lora_mid failure was this loop at 1 wv/SIMD).
// ---------------------------------------------------------------------------
__global__ __launch_bounds__(256) void hmid_kernel(
    const float* __restrict__ comb, const float* __restrict__ tpwg,
    const int* __restrict__ tpib, const float* __restrict__ Aup,
    float* __restrict__ hmid_g)
{
    int t = blockIdx.x, tid = threadIdx.x;
    __shared__ float combs[DD];
    combs[tid] = comb[(size_t)t*DD + tid];
    __syncthreads();
    int kp = tid >> 6, r = tid & 63;
    int p = tpib[t*4 + kp];
    const float* Ap = Aup + (size_t)p*(DD*RR) + r;
    float acc = 0.f;
    #pragma unroll 8
    for (int d = 0; d < DD; ++d)
        acc = fmaf(combs[d], Ap[(size_t)d*RR], acc);
    hmid_g[(size_t)(t*4 + kp)*RR + r] = acc * tpwg[t*4 + kp];
}

// ---------------------------------------------------------------------------
// LoRA apply: grid (PP, FFD/128, 16). Block = (pattern, ff-tile, 64-entry
// chunk). B tile (32KB) + transposed hm tile (17KB) in LDS; inner loop is
// 3x ds_read_b128 (2 broadcast) per 32 FMA -> VALU-bound.
// ---------------------------------------------------------------------------
__global__ __launch_bounds__(256) void lora_apply(
    const int* __restrict__ bin_count, const int* __restrict__ bin_entry,
    const float* __restrict__ hmid_g, const float* __restrict__ Bup,
    float* __restrict__ hpat4)
{
    int p = blockIdx.x, ff0 = blockIdx.y * 128;
    int base = blockIdx.z * 64;
    int cnt = bin_count[p];
    if (base >= cnt) return;
    int nt = cnt - base; if (nt > 64) nt = 64;
    int tid = threadIdx.x;

    __shared__ float Bs[RR][132];      // 33.8 KB
    __shared__ float hmT[RR][68];      // 17.4 KB, transposed: hmT[r][entry]
    __shared__ int es[64];

    // stage B tile (2048 float4)
    const float* Bp = Bup + (size_t)p*(RR*FFD) + ff0;
    #pragma unroll
    for (int e = 0; e < 8; ++e) {
        int lin = e*256 + tid;
        int r = lin >> 5, cg = lin & 31;
        *(float4*)&Bs[r][cg*4] = *(const float4*)&Bp[(size_t)r*FFD + cg*4];
    }
    if (tid < 64) es[tid] = (tid < nt) ? bin_entry[p*TT + base + tid] : -1;
    __syncthreads();
    // stage hm transposed (64 entries x 64 r)
    #pragma unroll
    for (int e = 0; e < 4; ++e) {
        int lin = e*256 + tid;         // 1024 float4
        int i = lin >> 4, rg = lin & 15;
        int ei = es[i];
        float4 hv = make_float4(0.f,0.f,0.f,0.f);
        if (ei >= 0) hv = *(const float4*)&hmid_g[(size_t)ei*RR + rg*4];
        hmT[rg*4+0][i] = hv.x;
        hmT[rg*4+1][i] = hv.y;
        hmT[rg*4+2][i] = hv.z;
        hmT[rg*4+3][i] = hv.w;
    }
    __syncthreads();

    int eg = tid >> 5, cg = tid & 31;  // 8 entries x 4 cols per thread
    float4 acc[8];
    #pragma unroll
    for (int j = 0; j < 8; ++j) acc[j] = make_float4(0.f,0.f,0.f,0.f);
    #pragma unroll 4
    for (int r = 0; r < RR; ++r) {
        float4 b  = *(const float4*)&Bs[r][cg*4];
        float4 h0 = *(const float4*)&hmT[r][eg*8];
        float4 h1 = *(const float4*)&hmT[r][eg*8+4];
        acc[0].x = fmaf(h0.x, b.x, acc[0].x); acc[0].y = fmaf(h0.x, b.y, acc[0].y);
        acc[0].z = fmaf(h0.x, b.z, acc[0].z); acc[0].w = fmaf(h0.x, b.w, acc[0].w);
        acc[1].x = fmaf(h0.y, b.x, acc[1].x); acc[1].y = fmaf(h0.y, b.y, acc[1].y);
        acc[1].z = fmaf(h0.y, b.z, acc[1].z); acc[1].w = fmaf(h0.y, b.w, acc[1].w);
        acc[2].x = fmaf(h0.z, b.x, acc[2].x); acc[2].y = fmaf(h0.z, b.y, acc[2].y);
        acc[2].z = fmaf(h0.z, b.z, acc[2].z); acc[2].w = fmaf(h0.z, b.w, acc[2].w);
        acc[3].x = fmaf(h0.w, b.x, acc[3].x); acc[3].y = fmaf(h0.w, b.y, acc[3].y);
        acc[3].z = fmaf(h0.w, b.z, acc[3].z); acc[3].w = fmaf(h0.w, b.w, acc[3].w);
        acc[4].x = fmaf(h1.x, b.x, acc[4].x); acc[4].y = fmaf(h1.x, b.y, acc[4].y);
        acc[4].z = fmaf(h1.x, b.z, acc[4].z); acc[4].w = fmaf(h1.x, b.w, acc[4].w);
        acc[5].x = fmaf(h1.y, b.x, acc[5].x); acc[5].y = fmaf(h1.y, b.y, acc[5].y);
        acc[5].z = fmaf(h1.y, b.z, acc[5].z); acc[5].w = fmaf(h1.y, b.w, acc[5].w);
        acc[6].x = fmaf(h1.z, b.x, acc[6].x); acc[6].y = fmaf(h1.z, b.y, acc[6].y);
        acc[6].z = fmaf(h1.z, b.z, acc[6].z); acc[6].w = fmaf(h1.z, b.w, acc[6].w);
        acc[7].x = fmaf(h1.w, b.x, acc[7].x); acc[7].y = fmaf(h1.w, b.y, acc[7].y);
        acc[7].z = fmaf(h1.w, b.z, acc[7].z); acc[7].w = fmaf(h1.w, b.w, acc[7].w);
    }
    #pragma unroll
    for (int j = 0; j < 8; ++j) {
        int e = es[eg*8+j];
        if (e >= 0) {
            int t = e >> 2, kp = e & 3;
            *(float4*)&hpat4[(size_t)kp*(TT*FFD) + (size_t)t*FFD + ff0 + cg*4] = acc[j];
        }
    }
}

// ---------------------------------------------------------------------------
extern "C" void kernel_launch(void* const* d_in, const int* in_sizes, int n_in,
                              void* d_out, int out_size, void* d_ws, size_t ws_size,
                              hipStream_t stream)
{
    const float* x        = (const float*)d_in[0];
    const float* g1       = (const float*)d_in[1];
    const float* b1       = (const float*)d_in[2];
    const float* g2       = (const float*)d_in[3];
    const float* b2       = (const float*)d_in[4];
    const float* Wq       = (const float*)d_in[5];
    const float* bq       = (const float*)d_in[6];
    const float* Wk       = (const float*)d_in[7];
    const float* bk       = (const float*)d_in[8];
    const float* Wv       = (const float*)d_in[9];
    const float* bv       = (const float*)d_in[10];
    const float* Wpath    = (const float*)d_in[11];
    const float* bpath    = (const float*)d_in[12];
    const float* neurons  = (const float*)d_in[13];
    const float* Wnq      = (const float*)d_in[14];
    const float* bnq      = (const float*)d_in[15];
    const float* Wnk      = (const float*)d_in[16];
    const float* bnk      = (const float*)d_in[17];
    const float* Wnv      = (const float*)d_in[18];
    const float* bnv      = (const float*)d_in[19];
    const float* PQ       = (const float*)d_in[20];
    const float* Aup      = (const float*)d_in[21];
    const float* Bup      = (const float*)d_in[22];
    const float* Wub      = (const float*)d_in[23];
    const float* bub      = (const float*)d_in[24];
    const float* Wd       = (const float*)d_in[25];
    const float* bd       = (const float*)d_in[26];

    float* out0    = (float*)d_out;              // [B,S,D] residual output
    float* out_idx = out0 + (size_t)TT*DD;       // [B,S,K] indices (as float)

    // workspace carve-up (floats)
    float* ws = (float*)d_ws;
    float* n1    = ws; ws += TT*DD;
    float* n2    = ws; ws += TT*DD;
    float* qb    = ws; ws += TT*DD;
    float* kb    = ws; ws += TT*DD;
    float* vb    = ws; ws += TT*DD;
    float* ctx   = ws; ws += TT*DD;
    float* ts    = ws; ws += TT*NN;
    float* cs    = ws; ws += TT*NN;
    float* nqa   = ws; ws += NN*DD;
    float* nka   = ws; ws += NN*DD;
    float* nva   = ws; ws += NN*DD;
    float* comb  = ws; ws += TT*DD;
    float* hpat4 = ws; ws += 4*TT*FFD;           // 4 slices (one per kp)
    float* hb    = ws; ws += TT*FFD;
    float* part  = ws; ws += 4*TT*DD;            // split-K partials for Wd
    float* hmidg = ws; ws += 4*TT*RR;            // hmid per entry e=(t<<2)|kp
    float* tpwg  = ws; ws += TT*KPP;
    int*   tpib  = (int*)ws; ws += TT*KPP;
    int*   binc  = (int*)ws; ws += 32;
    int*   bine  = (int*)ws; ws += 32*TT;

    dim3 blk(256);

    // 1. LayerNorms (+ zero bin counters)
    ln_kernel<<<TT, blk, 0, stream>>>(x, g1, b1, g2, b2, n1, n2, binc);

    // 2. All six D->D projections in one launch (QKV on n1, neuron q/k/v)
    {
        GemmSet sq{n1, Wq, bq, qb, 0, TT}, sk{n1, Wk, bk, kb, 0, TT},
                sv{n1, Wv, bv, vb, 0, TT},
                p0{neurons, Wnq, bnq, nqa, 0, NN}, p1{neurons, Wnk, bnk, nka, 0, NN},
                p2{neurons, Wnv, bnv, nva, 1, NN};
        gemm6_kernel<<<dim3(DD/64, TT/64, 6), blk, 0, stream>>>(sq, sk, sv, p0, p1, p2, DD, DD, 0);
    }

    // 3. Attention -> context  (flash-style, 256 blocks)
    attn_kernel<<<BB*HH*(SS/QT), blk, 0, stream>>>(qb, kb, vb, ctx);

    // 4. token/context scores vs neurons^T (M=1024,N=512,K=256, transB, z=2)
    {
        GemmSet s0{n1, neurons, nullptr, ts, 0, TT}, s1{ctx, neurons, nullptr, cs, 0, TT};
        gemm2_kernel<<<dim3(NN/64, TT/64, 2), blk, 0, stream>>>(s0, s1, NN, DD, 1);
    }

    // 5. fused per-token: route -> interaction FFN -> pattern select
    token_kernel<<<TT, blk, 0, stream>>>(n1, ctx, Wpath, bpath, ts, cs,
                                         neurons, nqa, nka, nva, n2, PQ,
                                         comb, tpwg, tpib, binc, bine, out_idx);

    // 6. hmid per (token, kp)  (block per token; high occupancy)
    hmid_kernel<<<TT, blk, 0, stream>>>(comb, tpwg, tpib, Aup, hmidg);

    // 7. LoRA apply (grouped by pattern, entry-chunked) -> hpat4 slices
    lora_apply<<<dim3(PP, FFD/128, 16), blk, 0, stream>>>(binc, bine, hmidg, Bup, hpat4);

    // 8. h = gelu(0.1*(comb@Wub+bub) + 0.9*sum(hpat4))   (M=1024,N=1024,K=256)
    gemm_kernel<<<dim3(FFD/64, TT/64), blk, 0, stream>>>(comb, Wub, bub, hpat4, hb, TT, FFD, DD, 0, 2);

    // 9. out = x + h@Wd + bd  via split-K(4) + combine  (M=1024,N=256,K=1024)
    gemm_splitk_kernel<<<dim3(DD/64, TT/64, 4), blk, 0, stream>>>(hb, Wd, part, TT, DD, FFD, FFD/4);
    combine_wd_kernel<<<TT*DD/256, blk, 0, stream>>>(part, x, bd, out0);
}

// Round 10
// 331.627 us; speedup vs baseline: 1.2489x; 1.0454x over previous
//
#include <hip/hip_runtime.h>
#include <hip/hip_bf16.h>
#include <math.h>

// Problem dims (fixed)
#define BB 2
#define SS 512
#define DD 256
#define FFD 1024
#define HH 4
#define NN 512
#define PP 32
#define KK 16
#define KPP 4
#define RR 64
#define DHH 64
#define TT (BB*SS)   // 1024 tokens
#define QT 16        // attn queries per block

// ---------------------------------------------------------------------------
// LayerNorm (+ zero the 32 bin counters from block 0). One block per token.
// ---------------------------------------------------------------------------
__global__ __launch_bounds__(256) void ln_kernel(
    const float* __restrict__ x,
    const float* __restrict__ g1, const float* __restrict__ b1,
    const float* __restrict__ g2, const float* __restrict__ b2,
    float* __restrict__ n1, float* __restrict__ n2,
    int* __restrict__ binc)
{
    int t = blockIdx.x;
    int d = threadIdx.x;
    if (t == 0 && d < 32) binc[d] = 0;
    __shared__ float red[256];
    float v = x[t*DD + d];
    red[d] = v; __syncthreads();
    for (int s = 128; s > 0; s >>= 1) { if (d < s) red[d] += red[d+s]; __syncthreads(); }
    float mu = red[0] * (1.0f/DD);
    __syncthreads();
    float dv = v - mu;
    red[d] = dv*dv; __syncthreads();
    for (int s = 128; s > 0; s >>= 1) { if (d < s) red[d] += red[d+s]; __syncthreads(); }
    float var = red[0] * (1.0f/DD);
    float r = 1.0f / sqrtf(var + 1e-5f);
    n1[t*DD+d] = dv*r*g1[d] + b1[d];
    n2[t*DD+d] = dv*r*g2[d] + b2[d];
}

// ---------------------------------------------------------------------------
// GEMM body: 64x64 tile, BK=32, 256 threads, register double-buffering.
//   mode 0: none; 1: sigmoid; 2: gelu(0.1*val+0.9*sum4slices(extra)); 3: val+extra
// ---------------------------------------------------------------------------
__device__ __forceinline__ void gemm_body(
    const float* __restrict__ A, const float* __restrict__ Bm,
    const float* __restrict__ bias, const float* __restrict__ extra,
    float* __restrict__ C, int M, int Nn, int Kk, int transB, int mode,
    int k0off, int kLen)
{
    __shared__ float As[2][32][68];   // As[buf][k][m] (transposed)
    __shared__ float Bs[2][32][68];   // Bs[buf][k][n]
    int bm = blockIdx.y * 64;
    int bn = blockIdx.x * 64;
    int tid = threadIdx.x;
    int tx = tid & 15, ty = tid >> 4;

    float4 pa[2], pb[2];

    #define LOAD_A(kbase) { \
        _Pragma("unroll") \
        for (int e = 0; e < 2; ++e) { \
            int r = e*32 + (tid>>3); int c4 = tid & 7; \
            pa[e] = *(const float4*)&A[(size_t)(bm + r)*Kk + (kbase) + c4*4]; \
        } }
    #define STORE_A(buf) { \
        _Pragma("unroll") \
        for (int e = 0; e < 2; ++e) { \
            int r = e*32 + (tid>>3); int c4 = tid & 7; \
            As[buf][c4*4+0][r] = pa[e].x; \
            As[buf][c4*4+1][r] = pa[e].y; \
            As[buf][c4*4+2][r] = pa[e].z; \
            As[buf][c4*4+3][r] = pa[e].w; \
        } }
    #define LOAD_B(kbase) { \
        if (transB == 0) { \
            _Pragma("unroll") \
            for (int e = 0; e < 2; ++e) { \
                int c = e*16 + (tid>>4); int n4 = tid & 15; \
                pb[e] = *(const float4*)&Bm[(size_t)((kbase) + c)*Nn + bn + n4*4]; \
            } \
        } else { \
            _Pragma("unroll") \
            for (int e = 0; e < 2; ++e) { \
                int r = e*32 + (tid>>3); int k4 = tid & 7; \
                pb[e] = *(const float4*)&Bm[(size_t)(bn + r)*Kk + (kbase) + k4*4]; \
            } \
        } }
    #define STORE_B(buf) { \
        if (transB == 0) { \
            _Pragma("unroll") \
            for (int e = 0; e < 2; ++e) { \
                int c = e*16 + (tid>>4); int n4 = tid & 15; \
                *(float4*)&Bs[buf][c][n4*4] = pb[e]; \
            } \
        } else { \
            _Pragma("unroll") \
            for (int e = 0; e < 2; ++e) { \
                int r = e*32 + (tid>>3); int k4 = tid & 7; \
                Bs[buf][k4*4+0][r] = pb[e].x; \
                Bs[buf][k4*4+1][r] = pb[e].y; \
                Bs[buf][k4*4+2][r] = pb[e].z; \
                Bs[buf][k4*4+3][r] = pb[e].w; \
            } \
        } }

    float acc[4][4] = {};
    int nk = kLen >> 5;   // BK=32

    LOAD_A(k0off); LOAD_B(k0off);
    STORE_A(0); STORE_B(0);
    __syncthreads();

    for (int kt = 0; kt < nk; ++kt) {
        int cur = kt & 1;
        if (kt + 1 < nk) { LOAD_A(k0off + (kt+1)*32); LOAD_B(k0off + (kt+1)*32); }
        #pragma unroll
        for (int kk = 0; kk < 32; ++kk) {
            float4 av = *(const float4*)&As[cur][kk][ty*4];
            float4 bv = *(const float4*)&Bs[cur][kk][tx*4];
            acc[0][0] = fmaf(av.x, bv.x, acc[0][0]);
            acc[0][1] = fmaf(av.x, bv.y, acc[0][1]);
            acc[0][2] = fmaf(av.x, bv.z, acc[0][2]);
            acc[0][3] = fmaf(av.x, bv.w, acc[0][3]);
            acc[1][0] = fmaf(av.y, bv.x, acc[1][0]);
            acc[1][1] = fmaf(av.y, bv.y, acc[1][1]);
            acc[1][2] = fmaf(av.y, bv.z, acc[1][2]);
            acc[1][3] = fmaf(av.y, bv.w, acc[1][3]);
            acc[2][0] = fmaf(av.z, bv.x, acc[2][0]);
            acc[2][1] = fmaf(av.z, bv.y, acc[2][1]);
            acc[2][2] = fmaf(av.z, bv.z, acc[2][2]);
            acc[2][3] = fmaf(av.z, bv.w, acc[2][3]);
            acc[3][0] = fmaf(av.w, bv.x, acc[3][0]);
            acc[3][1] = fmaf(av.w, bv.y, acc[3][1]);
            acc[3][2] = fmaf(av.w, bv.z, acc[3][2]);
            acc[3][3] = fmaf(av.w, bv.w, acc[3][3]);
        }
        if (kt + 1 < nk) {
            STORE_A(cur^1); STORE_B(cur^1);
            __syncthreads();
        }
    }

    #pragma unroll
    for (int i = 0; i < 4; ++i) {
        int m = bm + ty*4 + i;
        #pragma unroll
        for (int j = 0; j < 4; ++j) {
            int n = bn + tx*4 + j;
            float val = acc[i][j] + (bias ? bias[n] : 0.0f);
            if (mode == 1) {
                val = 1.0f / (1.0f + expf(-val));
            } else if (mode == 2) {
                size_t idx = (size_t)m*Nn + n;
                float hp = extra[idx] + extra[idx + (size_t)TT*FFD]
                         + extra[idx + 2*(size_t)TT*FFD] + extra[idx + 3*(size_t)TT*FFD];
                float z = 0.1f*val + 0.9f*hp;
                val = 0.5f*z*(1.0f + erff(z*0.70710678118654752f));
            } else if (mode == 3) {
                val = val + extra[(size_t)m*Nn+n];
            }
            C[(size_t)m*Nn + n] = val;
        }
    }
    #undef LOAD_A
    #undef STORE_A
    #undef LOAD_B
    #undef STORE_B
}

__global__ __launch_bounds__(256) void gemm_kernel(
    const float* __restrict__ A, const float* __restrict__ Bm,
    const float* __restrict__ bias, const float* __restrict__ extra,
    float* __restrict__ C, int M, int Nn, int Kk, int transB, int mode)
{
    gemm_body(A, Bm, bias, extra, C, M, Nn, Kk, transB, mode, 0, Kk);
}

struct GemmSet { const float* A; const float* B; const float* bias; float* C; int mode; int M; };

__global__ __launch_bounds__(256) void gemm2_kernel(
    GemmSet s0, GemmSet s1, int Nn, int Kk, int transB)
{
    GemmSet s = (blockIdx.z == 0) ? s0 : s1;
    if ((int)blockIdx.y * 64 >= s.M) return;
    gemm_body(s.A, s.B, s.bias, nullptr, s.C, s.M, Nn, Kk, transB, s.mode, 0, Kk);
}

__global__ __launch_bounds__(256) void gemm6_kernel(
    GemmSet s0, GemmSet s1, GemmSet s2, GemmSet s3, GemmSet s4, GemmSet s5,
    int Nn, int Kk, int transB)
{
    GemmSet s;
    switch (blockIdx.z) {
        case 0: s = s0; break;
        case 1: s = s1; break;
        case 2: s = s2; break;
        case 3: s = s3; break;
        case 4: s = s4; break;
        default: s = s5; break;
    }
    if ((int)blockIdx.y * 64 >= s.M) return;
    gemm_body(s.A, s.B, s.bias, nullptr, s.C, s.M, Nn, Kk, transB, s.mode, 0, Kk);
}

__global__ __launch_bounds__(256) void gemm_splitk_kernel(
    const float* __restrict__ A, const float* __restrict__ Bm,
    float* __restrict__ Cpart, int M, int Nn, int Kk, int kPerSplit)
{
    int sk = blockIdx.z;
    float* Cp = Cpart + (size_t)sk * M * Nn;
    gemm_body(A, Bm, nullptr, nullptr, Cp, M, Nn, Kk, 0, 0, sk*kPerSplit, kPerSplit);
}

__global__ __launch_bounds__(256) void combine_wd_kernel(
    const float* __restrict__ part, const float* __restrict__ x,
    const float* __restrict__ bd, float* __restrict__ out)
{
    int i = blockIdx.x*256 + threadIdx.x;
    int d = i & (DD-1);
    float s = x[i] + bd[d];
    s += part[i] + part[i + TT*DD] + part[i + 2*TT*DD] + part[i + 3*TT*DD];
    out[i] = s;
}

// ---------------------------------------------------------------------------
// Flash-style attention: block = (b, h, 16-query tile). 256 blocks, 256 thr.
// ---------------------------------------------------------------------------
__global__ __launch_bounds__(256) void attn_kernel(
    const float* __restrict__ q, const float* __restrict__ k,
    const float* __restrict__ v, float* __restrict__ ctx)
{
    int bi = blockIdx.x;
    int qt = bi & 31;
    int bh = bi >> 5;
    int h = bh & (HH-1);
    int b = bh >> 2;
    int tid = threadIdx.x;
    int qo = tid >> 4;
    int c  = tid & 15;

    __shared__ float Qs[QT][68];
    __shared__ float Kt[64][64];
    __shared__ float Vs[64][68];
    __shared__ float Ps[QT][68];

    {
        const float* qp = q + ((size_t)(b*SS + qt*QT + qo)*DD) + h*DHH + c*4;
        *(float4*)&Qs[qo][c*4] = *(const float4*)qp;
    }
    float O0=0.f, O1=0.f, O2=0.f, O3=0.f;
    float mreg = -3.4e38f, lreg = 0.f;

    for (int t = 0; t < 8; ++t) {
        if (t) __syncthreads();
        #pragma unroll
        for (int e = 0; e < 4; ++e) {
            int lin = e*256 + tid;
            int kr = lin & 63;
            int c4 = lin >> 6;
            const float* kp = k + ((size_t)(b*SS + t*64 + kr)*DD) + h*DHH + c4*4;
            float4 kv = *(const float4*)kp;
            Kt[c4*4+0][kr] = kv.x;
            Kt[c4*4+1][kr] = kv.y;
            Kt[c4*4+2][kr] = kv.z;
            Kt[c4*4+3][kr] = kv.w;
            int vr = lin >> 4;
            int vc = lin & 15;
            const float* vp = v + ((size_t)(b*SS + t*64 + vr)*DD) + h*DHH + vc*4;
            *(float4*)&Vs[vr][vc*4] = *(const float4*)vp;
        }
        __syncthreads();
        float s0=0.f, s1=0.f, s2=0.f, s3=0.f;
        #pragma unroll 8
        for (int d = 0; d < 64; ++d) {
            float qv = Qs[qo][d];
            float4 kv = *(const float4*)&Kt[d][c*4];
            s0 = fmaf(qv, kv.x, s0);
            s1 = fmaf(qv, kv.y, s1);
            s2 = fmaf(qv, kv.z, s2);
            s3 = fmaf(qv, kv.w, s3);
        }
        s0 *= 0.125f; s1 *= 0.125f; s2 *= 0.125f; s3 *= 0.125f;
        float mx = fmaxf(fmaxf(s0, s1), fmaxf(s2, s3));
        #pragma unroll
        for (int mk = 1; mk <= 8; mk <<= 1)
            mx = fmaxf(mx, __shfl_xor(mx, mk));
        float mnew = fmaxf(mreg, mx);
        float scl = __expf(mreg - mnew);
        float e0 = __expf(s0 - mnew), e1 = __expf(s1 - mnew),
              e2 = __expf(s2 - mnew), e3 = __expf(s3 - mnew);
        float esum = e0 + e1 + e2 + e3;
        #pragma unroll
        for (int mk = 1; mk <= 8; mk <<= 1)
            esum += __shfl_xor(esum, mk);
        lreg = lreg * scl + esum;
        mreg = mnew;
        float4 pw; pw.x = e0; pw.y = e1; pw.z = e2; pw.w = e3;
        *(float4*)&Ps[qo][c*4] = pw;
        __syncthreads();
        O0 *= scl; O1 *= scl; O2 *= scl; O3 *= scl;
        #pragma unroll 8
        for (int kk = 0; kk < 64; ++kk) {
            float pv = Ps[qo][kk];
            float4 vv = *(const float4*)&Vs[kk][c*4];
            O0 = fmaf(pv, vv.x, O0);
            O1 = fmaf(pv, vv.y, O1);
            O2 = fmaf(pv, vv.z, O2);
            O3 = fmaf(pv, vv.w, O3);
        }
    }
    float linv = 1.0f / lreg;
    float4 o4; o4.x = O0*linv; o4.y = O1*linv; o4.z = O2*linv; o4.w = O3*linv;
    *(float4*)(ctx + ((size_t)(b*SS + qt*QT + qo)*DD) + h*DHH + c*4) = o4;
}

// ---------------------------------------------------------------------------
// Fused per-token kernel v2: route -> interaction FFN -> pattern select.
//  - top-16 runs entirely in wave 0 (scores in registers, shfl butterfly,
//    zero barriers in the loop); top-4 likewise in 32 lanes.
//  - no nq LDS tile (q-rows read via 4-address broadcast global loads, L1-hot)
//  - LDS ~39KB -> 4 blocks/CU. 9 barriers total (was ~38).
// ---------------------------------------------------------------------------
__global__ __launch_bounds__(256) void token_kernel(
    const float* __restrict__ n1, const float* __restrict__ ctx,
    const float* __restrict__ Wpath, const float* __restrict__ bpath,
    const float* __restrict__ ts, const float* __restrict__ cs,
    const float* __restrict__ neurons,
    const float* __restrict__ nqa, const float* __restrict__ nka,
    const float* __restrict__ nva,
    const float* __restrict__ n2p, const float* __restrict__ PQ,
    float* __restrict__ comb_out, float* __restrict__ tpwg,
    int* __restrict__ tpib,
    int* __restrict__ binc, int* __restrict__ bine,
    float* __restrict__ out_idx)
{
    int t = blockIdx.x, tid = threadIdx.x;
    int wv = tid >> 6;

    __shared__ float nk[KK][DD+1];
    __shared__ float nv[KK][DD+1];
    __shared__ float ps[HH][KK][KK];
    __shared__ float mix[DD];
    __shared__ float psp[8][33];
    __shared__ float pw0[4], pw1[4];
    __shared__ float w01[2];
    __shared__ float selv[KK]; __shared__ int seli[KK];
    __shared__ float tw[KK];

    float a = n1[t*DD+tid], c = ctx[t*DD+tid];

    // ---- phase 1: path weights ----
    {
        float r0 = a * Wpath[tid*2+0] + c * Wpath[(DD+tid)*2+0];
        float r1 = a * Wpath[tid*2+1] + c * Wpath[(DD+tid)*2+1];
        #pragma unroll
        for (int off = 1; off < 64; off <<= 1) {
            r0 += __shfl_xor(r0, off);
            r1 += __shfl_xor(r1, off);
        }
        if ((tid & 63) == 0) { pw0[wv] = r0; pw1[wv] = r1; }
    }
    __syncthreads();                                    // b1
    if (tid == 0) {
        float l0 = pw0[0]+pw0[1]+pw0[2]+pw0[3] + bpath[0];
        float l1 = pw1[0]+pw1[1]+pw1[2]+pw1[3] + bpath[1];
        float mm = fmaxf(l0, l1);
        float e0 = expf(l0-mm), e1 = expf(l1-mm);
        float is = 1.0f/(e0+e1);
        w01[0] = e0*is; w01[1] = e1*is;
    }
    __syncthreads();                                    // b2

    // ---- phase 2: scores in wave-0 registers, top-16 with no barriers ----
    if (tid < 64) {
        float w0 = w01[0], w1 = w01[1];
        const float* tsp = ts + (size_t)t*NN;
        const float* csp = cs + (size_t)t*NN;
        float s0 = w0*tsp[tid      ] + w1*csp[tid      ];
        float s1 = w0*tsp[tid +  64] + w1*csp[tid +  64];
        float s2 = w0*tsp[tid + 128] + w1*csp[tid + 128];
        float s3 = w0*tsp[tid + 192] + w1*csp[tid + 192];
        float s4 = w0*tsp[tid + 256] + w1*csp[tid + 256];
        float s5 = w0*tsp[tid + 320] + w1*csp[tid + 320];
        float s6 = w0*tsp[tid + 384] + w1*csp[tid + 384];
        float s7 = w0*tsp[tid + 448] + w1*csp[tid + 448];
        #pragma unroll
        for (int it = 0; it < KK; ++it) {
            float bv = s0; int bc = 0;
            if (s1 > bv) { bv = s1; bc = 1; }
            if (s2 > bv) { bv = s2; bc = 2; }
            if (s3 > bv) { bv = s3; bc = 3; }
            if (s4 > bv) { bv = s4; bc = 4; }
            if (s5 > bv) { bv = s5; bc = 5; }
            if (s6 > bv) { bv = s6; bc = 6; }
            if (s7 > bv) { bv = s7; bc = 7; }
            int bi = bc*64 + tid;
            #pragma unroll
            for (int off = 1; off < 64; off <<= 1) {
                float ov = __shfl_xor(bv, off);
                int   oi = __shfl_xor(bi, off);
                if (ov > bv || (ov == bv && oi < bi)) { bv = ov; bi = oi; }
            }
            if ((bi & 63) == tid) {
                switch (bi >> 6) {
                    case 0: s0 = -3.4e38f; break;
                    case 1: s1 = -3.4e38f; break;
                    case 2: s2 = -3.4e38f; break;
                    case 3: s3 = -3.4e38f; break;
                    case 4: s4 = -3.4e38f; break;
                    case 5: s5 = -3.4e38f; break;
                    case 6: s6 = -3.4e38f; break;
                    default: s7 = -3.4e38f; break;
                }
            }
            if (tid == 0) { selv[it] = bv; seli[it] = bi; }
        }
        if (tid == 0) {
            float mx = selv[0];
            float e[KK]; float sum = 0.f;
            #pragma unroll
            for (int i = 0; i < KK; ++i) { e[i] = expf(selv[i]-mx); sum += e[i]; }
            float is = 1.0f/sum;
            #pragma unroll
            for (int i = 0; i < KK; ++i) tw[i] = e[i]*is;
        }
    }
    __syncthreads();                                    // b3

    if (tid < KK) out_idx[t*KK + tid] = (float)seli[tid];

    // ---- phase 3: interaction FFN ----
    for (int i = 0; i < KK; ++i) {
        int idx = seli[i];
        nk[i][tid] = nka[idx*DD+tid];
        nv[i][tid] = nva[idx*DD+tid];
    }
    __syncthreads();                                    // b4
    #pragma unroll
    for (int r = 0; r < 4; ++r) {                       // h == r
        int j = tid & 15, i = tid >> 4;
        const float* qg = nqa + (size_t)seli[i]*DD + r*DHH;   // broadcast (4/wave)
        const float* kp = &nk[j][r*DHH];
        float acc = 0.f;
        #pragma unroll 8
        for (int d = 0; d < DHH; ++d) acc = fmaf(qg[d], kp[d], acc);
        ps[r][i][j] = acc * 0.125f;
    }
    __syncthreads();                                    // b5
    if (tid < 64) {
        int h = tid >> 4, i = tid & 15;
        float mx = -3.4e38f;
        for (int j = 0; j < KK; ++j) mx = fmaxf(mx, ps[h][i][j]);
        float sum = 0.f;
        for (int j = 0; j < KK; ++j) { float e = expf(ps[h][i][j]-mx); ps[h][i][j] = e; sum += e; }
        float is = 1.0f/sum;
        for (int j = 0; j < KK; ++j) ps[h][i][j] *= is;
    }
    __syncthreads();                                    // b6
    float agg = 0.f;
    {
        int d = tid, h = d >> 6;
        for (int i = 0; i < KK; ++i) {
            float g = 0.f;
            #pragma unroll
            for (int j = 0; j < KK; ++j) g = fmaf(ps[h][i][j], nv[j][d], g);
            agg += tw[i] * neurons[seli[i]*DD + d] * g;
        }
    }

    // ---- phase 4: pattern select ----
    mix[tid] = 0.03125f * agg + 0.5f * c;   // 0.5/sqrt(256) = 0.03125
    float cb = n2p[t*DD+tid] + agg;
    comb_out[t*DD+tid] = cb;
    __syncthreads();                                    // b7
    {
        int p = tid & 31, g = tid >> 5;
        const float* pq = PQ + p*DD + g*32;
        const float* mp = mix + g*32;
        float acc = 0.f;
        #pragma unroll
        for (int d = 0; d < 32; ++d) acc = fmaf(mp[d], pq[d], acc);
        psp[g][p] = acc;
    }
    __syncthreads();                                    // b8
    if (tid < 32) {
        float sv = 0.f;
        #pragma unroll
        for (int g = 0; g < 8; ++g) sv += psp[g][tid];
        float v0, v1, v2, v3; int i0, i1, i2, i3;
        #define TOP1(VV, II) { \
            float bv = sv; int bi = tid; \
            _Pragma("unroll") \
            for (int off = 1; off < 32; off <<= 1) { \
                float ov = __shfl_xor(bv, off); \
                int   oi = __shfl_xor(bi, off); \
                if (ov > bv || (ov == bv && oi < bi)) { bv = ov; bi = oi; } \
            } \
            if (bi == tid) sv = -3.4e38f; \
            VV = bv; II = bi; }
        TOP1(v0, i0) TOP1(v1, i1) TOP1(v2, i2) TOP1(v3, i3)
        #undef TOP1
        if (tid < KPP) {
            float vs = (tid==0) ? v0 : (tid==1) ? v1 : (tid==2) ? v2 : v3;
            int   pi = (tid==0) ? i0 : (tid==1) ? i1 : (tid==2) ? i2 : i3;
            float e0 = expf(v0-v0), e1 = expf(v1-v0), e2 = expf(v2-v0), e3 = expf(v3-v0);
            float is = 1.0f/(e0+e1+e2+e3);
            tpwg[t*4+tid] = expf(vs - v0) * is;
            tpib[t*4+tid] = pi;
            int slot = atomicAdd(&binc[pi], 1);
            bine[pi*TT + slot] = (t << 2) | tid;
        }
    }
}

// ---------------------------------------------------------------------------
// hmid: block per token (1024 blocks, tiny LDS -> high occupancy).
// ---------------------------------------------------------------------------
__global__ __launch_bounds__(256) void hmid_kernel(
    const float* __restrict__ comb, const float* __restrict__ tpwg,
    const int* __restrict__ tpib, const float* __restrict__ Aup,
    float* __restrict__ hmid_g)
{
    int t = blockIdx.x, tid = threadIdx.x;
    __shared__ float combs[DD];
    combs[tid] = comb[(size_t)t*DD + tid];
    __syncthreads();
    int kp = tid >> 6, r = tid & 63;
    int p = tpib[t*4 + kp];
    const float* Ap = Aup + (size_t)p*(DD*RR) + r;
    float acc = 0.f;
    #pragma unroll 8
    for (int d = 0; d < DD; ++d)
        acc = fmaf(combs[d], Ap[(size_t)d*RR], acc);
    hmid_g[(size_t)(t*4 + kp)*RR + r] = acc * tpwg[t*4 + kp];
}

// ---------------------------------------------------------------------------
// LoRA apply: grid (PP, FFD/128, 16). Block = (pattern, ff-tile, 64-entry
// chunk). B tile (32KB) + transposed hm tile (17KB) in LDS.
// ---------------------------------------------------------------------------
__global__ __launch_bounds__(256) void lora_apply(
    const int* __restrict__ bin_count, const int* __restrict__ bin_entry,
    const float* __restrict__ hmid_g, const float* __restrict__ Bup,
    float* __restrict__ hpat4)
{
    int p = blockIdx.x, ff0 = blockIdx.y * 128;
    int base = blockIdx.z * 64;
    int cnt = bin_count[p];
    if (base >= cnt) return;
    int nt = cnt - base; if (nt > 64) nt = 64;
    int tid = threadIdx.x;

    __shared__ float Bs[RR][132];      // 33.8 KB
    __shared__ float hmT[RR][68];      // 17.4 KB, transposed: hmT[r][entry]
    __shared__ int es[64];

    const float* Bp = Bup + (size_t)p*(RR*FFD) + ff0;
    #pragma unroll
    for (int e = 0; e < 8; ++e) {
        int lin = e*256 + tid;
        int r = lin >> 5, cg = lin & 31;
        *(float4*)&Bs[r][cg*4] = *(const float4*)&Bp[(size_t)r*FFD + cg*4];
    }
    if (tid < 64) es[tid] = (tid < nt) ? bin_entry[p*TT + base + tid] : -1;
    __syncthreads();
    #pragma unroll
    for (int e = 0; e < 4; ++e) {
        int lin = e*256 + tid;         // 1024 float4
        int i = lin >> 4, rg = lin & 15;
        int ei = es[i];
        float4 hv = make_float4(0.f,0.f,0.f,0.f);
        if (ei >= 0) hv = *(const float4*)&hmid_g[(size_t)ei*RR + rg*4];
        hmT[rg*4+0][i] = hv.x;
        hmT[rg*4+1][i] = hv.y;
        hmT[rg*4+2][i] = hv.z;
        hmT[rg*4+3][i] = hv.w;
    }
    __syncthreads();

    int eg = tid >> 5, cg = tid & 31;  // 8 entries x 4 cols per thread
    float4 acc[8];
    #pragma unroll
    for (int j = 0; j < 8; ++j) acc[j] = make_float4(0.f,0.f,0.f,0.f);
    #pragma unroll 4
    for (int r = 0; r < RR; ++r) {
        float4 b  = *(const float4*)&Bs[r][cg*4];
        float4 h0 = *(const float4*)&hmT[r][eg*8];
        float4 h1 = *(const float4*)&hmT[r][eg*8+4];
        acc[0].x = fmaf(h0.x, b.x, acc[0].x); acc[0].y = fmaf(h0.x, b.y, acc[0].y);
        acc[0].z = fmaf(h0.x, b.z, acc[0].z); acc[0].w = fmaf(h0.x, b.w, acc[0].w);
        acc[1].x = fmaf(h0.y, b.x, acc[1].x); acc[1].y = fmaf(h0.y, b.y, acc[1].y);
        acc[1].z = fmaf(h0.y, b.z, acc[1].z); acc[1].w = fmaf(h0.y, b.w, acc[1].w);
        acc[2].x = fmaf(h0.z, b.x, acc[2].x); acc[2].y = fmaf(h0.z, b.y, acc[2].y);
        acc[2].z = fmaf(h0.z, b.z, acc[2].z); acc[2].w = fmaf(h0.z, b.w, acc[2].w);
        acc[3].x = fmaf(h0.w, b.x, acc[3].x); acc[3].y = fmaf(h0.w, b.y, acc[3].y);
        acc[3].z = fmaf(h0.w, b.z, acc[3].z); acc[3].w = fmaf(h0.w, b.w, acc[3].w);
        acc[4].x = fmaf(h1.x, b.x, acc[4].x); acc[4].y = fmaf(h1.x, b.y, acc[4].y);
        acc[4].z = fmaf(h1.x, b.z, acc[4].z); acc[4].w = fmaf(h1.x, b.w, acc[4].w);
        acc[5].x = fmaf(h1.y, b.x, acc[5].x); acc[5].y = fmaf(h1.y, b.y, acc[5].y);
        acc[5].z = fmaf(h1.y, b.z, acc[5].z); acc[5].w = fmaf(h1.y, b.w, acc[5].w);
        acc[6].x = fmaf(h1.z, b.x, acc[6].x); acc[6].y = fmaf(h1.z, b.y, acc[6].y);
        acc[6].z = fmaf(h1.z, b.z, acc[6].z); acc[6].w = fmaf(h1.z, b.w, acc[6].w);
        acc[7].x = fmaf(h1.w, b.x, acc[7].x); acc[7].y = fmaf(h1.w, b.y, acc[7].y);
        acc[7].z = fmaf(h1.w, b.z, acc[7].z); acc[7].w = fmaf(h1.w, b.w, acc[7].w);
    }
    #pragma unroll
    for (int j = 0; j < 8; ++j) {
        int e = es[eg*8+j];
        if (e >= 0) {
            int t = e >> 2, kp = e & 3;
            *(float4*)&hpat4[(size_t)kp*(TT*FFD) + (size_t)t*FFD + ff0 + cg*4] = acc[j];
        }
    }
}

// ---------------------------------------------------------------------------
extern "C" void kernel_launch(void* const* d_in, const int* in_sizes, int n_in,
                              void* d_out, int out_size, void* d_ws, size_t ws_size,
                              hipStream_t stream)
{
    const float* x        = (const float*)d_in[0];
    const float* g1       = (const float*)d_in[1];
    const float* b1       = (const float*)d_in[2];
    const float* g2       = (const float*)d_in[3];
    const float* b2       = (const float*)d_in[4];
    const float* Wq       = (const float*)d_in[5];
    const float* bq       = (const float*)d_in[6];
    const float* Wk       = (const float*)d_in[7];
    const float* bk       = (const float*)d_in[8];
    const float* Wv       = (const float*)d_in[9];
    const float* bv       = (const float*)d_in[10];
    const float* Wpath    = (const float*)d_in[11];
    const float* bpath    = (const float*)d_in[12];
    const float* neurons  = (const float*)d_in[13];
    const float* Wnq      = (const float*)d_in[14];
    const float* bnq      = (const float*)d_in[15];
    const float* Wnk      = (const float*)d_in[16];
    const float* bnk      = (const float*)d_in[17];
    const float* Wnv      = (const float*)d_in[18];
    const float* bnv      = (const float*)d_in[19];
    const float* PQ       = (const float*)d_in[20];
    const float* Aup      = (const float*)d_in[21];
    const float* Bup      = (const float*)d_in[22];
    const float* Wub      = (const float*)d_in[23];
    const float* bub      = (const float*)d_in[24];
    const float* Wd       = (const float*)d_in[25];
    const float* bd       = (const float*)d_in[26];

    float* out0    = (float*)d_out;              // [B,S,D] residual output
    float* out_idx = out0 + (size_t)TT*DD;       // [B,S,K] indices (as float)

    // workspace carve-up (floats)
    float* ws = (float*)d_ws;
    float* n1    = ws; ws += TT*DD;
    float* n2    = ws; ws += TT*DD;
    float* qb    = ws; ws += TT*DD;
    float* kb    = ws; ws += TT*DD;
    float* vb    = ws; ws += TT*DD;
    float* ctx   = ws; ws += TT*DD;
    float* ts    = ws; ws += TT*NN;
    float* cs    = ws; ws += TT*NN;
    float* nqa   = ws; ws += NN*DD;
    float* nka   = ws; ws += NN*DD;
    float* nva   = ws; ws += NN*DD;
    float* comb  = ws; ws += TT*DD;
    float* hpat4 = ws; ws += 4*TT*FFD;           // 4 slices (one per kp)
    float* hb    = ws; ws += TT*FFD;
    float* part  = ws; ws += 4*TT*DD;            // split-K partials for Wd
    float* hmidg = ws; ws += 4*TT*RR;            // hmid per entry e=(t<<2)|kp
    float* tpwg  = ws; ws += TT*KPP;
    int*   tpib  = (int*)ws; ws += TT*KPP;
    int*   binc  = (int*)ws; ws += 32;
    int*   bine  = (int*)ws; ws += 32*TT;

    dim3 blk(256);

    // 1. LayerNorms (+ zero bin counters)
    ln_kernel<<<TT, blk, 0, stream>>>(x, g1, b1, g2, b2, n1, n2, binc);

    // 2. All six D->D projections in one launch (QKV on n1, neuron q/k/v)
    {
        GemmSet sq{n1, Wq, bq, qb, 0, TT}, sk{n1, Wk, bk, kb, 0, TT},
                sv{n1, Wv, bv, vb, 0, TT},
                p0{neurons, Wnq, bnq, nqa, 0, NN}, p1{neurons, Wnk, bnk, nka, 0, NN},
                p2{neurons, Wnv, bnv, nva, 1, NN};
        gemm6_kernel<<<dim3(DD/64, TT/64, 6), blk, 0, stream>>>(sq, sk, sv, p0, p1, p2, DD, DD, 0);
    }

    // 3. Attention -> context  (flash-style, 256 blocks)
    attn_kernel<<<BB*HH*(SS/QT), blk, 0, stream>>>(qb, kb, vb, ctx);

    // 4. token/context scores vs neurons^T (M=1024,N=512,K=256, transB, z=2)
    {
        GemmSet s0{n1, neurons, nullptr, ts, 0, TT}, s1{ctx, neurons, nullptr, cs, 0, TT};
        gemm2_kernel<<<dim3(NN/64, TT/64, 2), blk, 0, stream>>>(s0, s1, NN, DD, 1);
    }

    // 5. fused per-token: route -> interaction FFN -> pattern select
    token_kernel<<<TT, blk, 0, stream>>>(n1, ctx, Wpath, bpath, ts, cs,
                                         neurons, nqa, nka, nva, n2, PQ,
                                         comb, tpwg, tpib, binc, bine, out_idx);

    // 6. hmid per (token, kp)  (block per token; high occupancy)
    hmid_kernel<<<TT, blk, 0, stream>>>(comb, tpwg, tpib, Aup, hmidg);

    // 7. LoRA apply (grouped by pattern, entry-chunked) -> hpat4 slices
    lora_apply<<<dim3(PP, FFD/128, 16), blk, 0, stream>>>(binc, bine, hmidg, Bup, hpat4);

    // 8. h = gelu(0.1*(comb@Wub+bub) + 0.9*sum(hpat4))   (M=1024,N=1024,K=256)
    gemm_kernel<<<dim3(FFD/64, TT/64), blk, 0, stream>>>(comb, Wub, bub, hpat4, hb, TT, FFD, DD, 0, 2);

    // 9. out = x + h@Wd + bd  via split-K(4) + combine  (M=1024,N=256,K=1024)
    gemm_splitk_kernel<<<dim3(DD/64, TT/64, 4), blk, 0, stream>>>(hb, Wd, part, TT, DD, FFD, FFD/4);
    combine_wd_kernel<<<TT*DD/256, blk, 0, stream>>>(part, x, bd, out0);
}